// Round 1
// baseline (889.020 us; speedup 1.0000x reference)
//
#include <hip/hip_runtime.h>

typedef unsigned short ushort_t;
typedef unsigned short ushort8 __attribute__((ext_vector_type(8)));
typedef __bf16 bf16x8 __attribute__((ext_vector_type(8)));
typedef float f32x4 __attribute__((ext_vector_type(4)));

#define DEV __device__ __forceinline__

// ---------- helpers ----------
DEV ushort_t f2bf(float f) {
  unsigned u = __builtin_bit_cast(unsigned, f);
  u += 0x7FFFu + ((u >> 16) & 1u);   // RNE (no NaNs in this workload)
  return (ushort_t)(u >> 16);
}
DEV float bf2f(ushort_t u) {
  return __builtin_bit_cast(float, ((unsigned)u) << 16);
}
DEV void gload_lds16(const void* g, void* s) {
  // LDS dest is wave-uniform base + lane*16 (guide §5); generic->AS3 via
  // low-32 truncation (addrspacecast lowering is trunc on amdgcn).
  __builtin_amdgcn_global_load_lds(
      (__attribute__((address_space(1))) void*)(size_t)g,
      (__attribute__((address_space(3))) void*)(size_t)s, 16, 0, 0);
}
DEV f32x4 mfma_bf16(ushort8 a, ushort8 b, f32x4 c) {
  return __builtin_amdgcn_mfma_f32_16x16x32_bf16(
      __builtin_bit_cast(bf16x8, a), __builtin_bit_cast(bf16x8, b), c, 0, 0, 0);
}

// ---------- 1) f32 -> bf16 cast ----------
__global__ void cast_bf16(const float4* __restrict__ in,
                          ushort4* __restrict__ out, int n4) {
  int stride = gridDim.x * blockDim.x;
  for (int i = blockIdx.x * blockDim.x + threadIdx.x; i < n4; i += stride) {
    float4 v = in[i];
    out[i] = make_ushort4(f2bf(v.x), f2bf(v.y), f2bf(v.z), f2bf(v.w));
  }
}

// ---------- 2) GEMM: C[m][n] = sum_k A[m][k] * Bw[n][k] (+bias) ----------
// m97 structure: 128x128 tile, BK=32, 4 waves (2x2), 4x4 frags/wave,
// global_load_lds width-16 staging, 2 barriers per K-step.
template <int OUT_BF16, int ADD_BIAS>
__global__ __launch_bounds__(256)
void gemm_bt(const ushort_t* __restrict__ A, const ushort_t* __restrict__ Bw,
             const float* __restrict__ bias, void* __restrict__ Cp,
             int M, int N, int K) {
  __shared__ ushort_t As[128 * 32];
  __shared__ ushort_t Bs[128 * 32];
  const int tid = threadIdx.x;
  const int w = tid >> 6, l = tid & 63;
  const int g = l >> 4, r = l & 15;
  const int wr = w >> 1, wc = w & 1;
  const int m0 = blockIdx.y * 128, n0 = blockIdx.x * 128;

  f32x4 acc[4][4];
#pragma unroll
  for (int i = 0; i < 4; ++i)
#pragma unroll
    for (int j = 0; j < 4; ++j) acc[i][j] = f32x4{0.f, 0.f, 0.f, 0.f};

  for (int k0 = 0; k0 < K; k0 += 32) {
    __syncthreads();  // all waves done reading previous tile
#pragma unroll
    for (int i = 0; i < 2; ++i) {
      int ch = w * 64 + i * 256 + l;           // 16B chunk id in [0,512)
      int row = ch >> 2, off = (ch & 3) * 8;   // 4 chunks per 32-elem row
      gload_lds16(A + (size_t)(m0 + row) * K + k0 + off,
                  As + (size_t)(w * 64 + i * 256) * 8);
      gload_lds16(Bw + (size_t)(n0 + row) * K + k0 + off,
                  Bs + (size_t)(w * 64 + i * 256) * 8);
    }
    __syncthreads();  // vmcnt(0) drained by compiler -> tiles ready

    ushort8 av[4], bv[4];
#pragma unroll
    for (int mi = 0; mi < 4; ++mi)
      av[mi] = *(const ushort8*)(As + (wr * 64 + mi * 16 + r) * 32 + g * 8);
#pragma unroll
    for (int ni = 0; ni < 4; ++ni)
      bv[ni] = *(const ushort8*)(Bs + (wc * 64 + ni * 16 + r) * 32 + g * 8);
#pragma unroll
    for (int mi = 0; mi < 4; ++mi)
#pragma unroll
      for (int ni = 0; ni < 4; ++ni)
        acc[mi][ni] = mfma_bf16(av[mi], bv[ni], acc[mi][ni]);
  }

#pragma unroll
  for (int mi = 0; mi < 4; ++mi) {
#pragma unroll
    for (int ni = 0; ni < 4; ++ni) {
#pragma unroll
      for (int j = 0; j < 4; ++j) {
        int row = m0 + wr * 64 + mi * 16 + g * 4 + j;  // D: row=4g+j
        int col = n0 + wc * 64 + ni * 16 + r;          // D: col=lane&15
        float v = acc[mi][ni][j];
        if (ADD_BIAS) v += bias[col];
        if (OUT_BF16)
          ((ushort_t*)Cp)[(size_t)row * N + col] = f2bf(v);
        else
          ((float*)Cp)[(size_t)row * N + col] = v;
      }
    }
  }
}

// ---------- 3) per-head RMSNorm + RoPE + QKV split ----------
// one wave per (b,l,h); lane = d-pair index (d=2*lane, 2*lane+1)
__global__ __launch_bounds__(256)
void norm_rope(const ushort_t* __restrict__ qkv, const float* __restrict__ pe,
               const float* __restrict__ qs, const float* __restrict__ ksc,
               ushort_t* __restrict__ qb, ushort_t* __restrict__ kb,
               ushort_t* __restrict__ vb) {
  const int gw = blockIdx.x * 4 + (threadIdx.x >> 6);  // [0, 4096*24)
  const int lane = threadIdx.x & 63;
  const int h = gw % 24;
  const int bl = gw / 24;              // b*2048 + l
  const int b = bl >> 11, lp = bl & 2047;
  const int i2 = lane * 2;

  const float4 p4 = *(const float4*)(pe + (size_t)bl * 256 + lane * 4);
  const size_t src = (size_t)bl * 9216 + h * 128 + i2;
  const size_t dst = ((size_t)(b * 24 + h) * 2048 + lp) * 128 + i2;

  const float sq0 = qs[i2], sq1 = qs[i2 + 1];
  const float sk0 = ksc[i2], sk1 = ksc[i2 + 1];
  const float INV_SQRT_D = 0.08838834764831845f;

  {  // Q: rmsnorm + rope + pre-scale by 1/sqrt(D)
    unsigned u = *(const unsigned*)(qkv + src);
    float x0 = bf2f((ushort_t)(u & 0xFFFFu)), x1 = bf2f((ushort_t)(u >> 16));
    float ss = x0 * x0 + x1 * x1;
#pragma unroll
    for (int m = 32; m; m >>= 1) ss += __shfl_xor(ss, m, 64);
    float rr = rsqrtf(ss * (1.f / 128.f) + 1e-6f);
    float y0 = x0 * rr * sq0, y1 = x1 * rr * sq1;
    float o0 = (p4.x * y0 + p4.y * y1) * INV_SQRT_D;
    float o1 = (p4.z * y0 + p4.w * y1) * INV_SQRT_D;
    *(unsigned*)(qb + dst) = (unsigned)f2bf(o0) | ((unsigned)f2bf(o1) << 16);
  }
  {  // K: rmsnorm + rope
    unsigned u = *(const unsigned*)(qkv + src + 3072);
    float x0 = bf2f((ushort_t)(u & 0xFFFFu)), x1 = bf2f((ushort_t)(u >> 16));
    float ss = x0 * x0 + x1 * x1;
#pragma unroll
    for (int m = 32; m; m >>= 1) ss += __shfl_xor(ss, m, 64);
    float rr = rsqrtf(ss * (1.f / 128.f) + 1e-6f);
    float y0 = x0 * rr * sk0, y1 = x1 * rr * sk1;
    float o0 = p4.x * y0 + p4.y * y1;
    float o1 = p4.z * y0 + p4.w * y1;
    *(unsigned*)(kb + dst) = (unsigned)f2bf(o0) | ((unsigned)f2bf(o1) << 16);
  }
  // V: straight copy into [B,H,L,D]
  *(unsigned*)(vb + dst) = *(const unsigned*)(qkv + src + 6144);
}

// ---------- 4) flash attention: 64 q-rows x one (b,h) per block ----------
__global__ __launch_bounds__(256)
void attn_fwd(const ushort_t* __restrict__ qb, const ushort_t* __restrict__ kb,
              const ushort_t* __restrict__ vb, ushort_t* __restrict__ ob) {
  __shared__ ushort_t Ks[64 * 128];   // [key][d], XOR-swizzled
  __shared__ ushort_t Vt[128 * 72];   // [d][key], +8 pad
  __shared__ ushort_t Ps[4][16 * 72]; // per-wave P, +8 pad
  const int tid = threadIdx.x;
  const int w = tid >> 6, l = tid & 63;
  const int g = l >> 4, c = l & 15;
  const int bh = blockIdx.y;
  const int q0 = blockIdx.x * 64;

  // Q fragments (A-frag: row=lane&15 of this wave's 16-row strip, k=d)
  const ushort_t* qrow = qb + ((size_t)bh * 2048 + q0 + w * 16 + c) * 128;
  ushort8 a_q[4];
#pragma unroll
  for (int dc = 0; dc < 4; ++dc)
    a_q[dc] = *(const ushort8*)(qrow + dc * 32 + g * 8);

  float m_j[4], l_j[4];
#pragma unroll
  for (int j = 0; j < 4; ++j) { m_j[j] = -3.4e38f; l_j[j] = 0.f; }
  f32x4 o_acc[8];
#pragma unroll
  for (int dt = 0; dt < 8; ++dt) o_acc[dt] = f32x4{0.f, 0.f, 0.f, 0.f};

  const ushort_t* kbase = kb + (size_t)bh * 2048 * 128;
  const ushort_t* vbase = vb + (size_t)bh * 2048 * 128;

  for (int kt = 0; kt < 2048; kt += 64) {
    __syncthreads();
    // stage K tile, swizzled: byte ^= (row&7)<<4
#pragma unroll
    for (int i = 0; i < 4; ++i) {
      int ch = tid + i * 256;                // [0,1024)
      int row = ch >> 4, cb = ch & 15;
      ushort8 d = *(const ushort8*)(kbase + (size_t)(kt + row) * 128 + cb * 8);
      int ba = (row * 256 + cb * 16) ^ ((row & 7) << 4);
      *(ushort8*)((char*)Ks + ba) = d;
    }
    // stage V transposed: Vt[d][key] (pairs of keys -> b32 writes)
#pragma unroll
    for (int i = 0; i < 2; ++i) {
      int pc = tid + i * 256;                // [0,512)
      int kp = pc >> 4, doct = pc & 15;
      ushort8 v0 = *(const ushort8*)(vbase + (size_t)(kt + kp * 2) * 128 + doct * 8);
      ushort8 v1 = *(const ushort8*)(vbase + (size_t)(kt + kp * 2 + 1) * 128 + doct * 8);
#pragma unroll
      for (int j = 0; j < 8; ++j) {
        unsigned pair = (unsigned)v0[j] | ((unsigned)v1[j] << 16);
        *(unsigned*)(Vt + (doct * 8 + j) * 72 + kp * 2) = pair;
      }
    }
    __syncthreads();

    // S = Q K^T  (B-frag: col=key=kg*16+c, k=d)
    f32x4 sf[4];
#pragma unroll
    for (int kg = 0; kg < 4; ++kg) {
      f32x4 acc = f32x4{0.f, 0.f, 0.f, 0.f};
#pragma unroll
      for (int dc = 0; dc < 4; ++dc) {
        int key = kg * 16 + c;
        int ba = (key * 256 + (dc * 32 + g * 8) * 2) ^ ((key & 7) << 4);
        ushort8 bv = *(const ushort8*)((char*)Ks + ba);
        acc = mfma_bf16(a_q[dc], bv, acc);
      }
      sf[kg] = acc;
    }

    // online softmax; lane owns rows 4g+j, cols kg*16+c
    float fs[4];
#pragma unroll
    for (int j = 0; j < 4; ++j) {
      float v = fmaxf(fmaxf(sf[0][j], sf[1][j]), fmaxf(sf[2][j], sf[3][j]));
      v = fmaxf(v, __shfl_xor(v, 1, 64));
      v = fmaxf(v, __shfl_xor(v, 2, 64));
      v = fmaxf(v, __shfl_xor(v, 4, 64));
      v = fmaxf(v, __shfl_xor(v, 8, 64));
      float mn = fmaxf(m_j[j], v);
      fs[j] = __expf(m_j[j] - mn);
      m_j[j] = mn;
      float rs = 0.f;
#pragma unroll
      for (int kg = 0; kg < 4; ++kg) {
        float p = __expf(sf[kg][j] - mn);
        sf[kg][j] = p;
        rs += p;
      }
      rs += __shfl_xor(rs, 1, 64);
      rs += __shfl_xor(rs, 2, 64);
      rs += __shfl_xor(rs, 4, 64);
      rs += __shfl_xor(rs, 8, 64);
      l_j[j] = l_j[j] * fs[j] + rs;
    }
#pragma unroll
    for (int dt = 0; dt < 8; ++dt)
#pragma unroll
      for (int j = 0; j < 4; ++j) o_acc[dt][j] *= fs[j];

    // P (D-frag layout) -> LDS -> reload as A-frags (same-wave DS is in-order)
    ushort_t* Pw = Ps[w];
#pragma unroll
    for (int kg = 0; kg < 4; ++kg)
#pragma unroll
      for (int j = 0; j < 4; ++j)
        Pw[(g * 4 + j) * 72 + kg * 16 + c] = f2bf(sf[kg][j]);
    ushort8 a_p[2];
#pragma unroll
    for (int kk = 0; kk < 2; ++kk)
      a_p[kk] = *(const ushort8*)(Pw + c * 72 + kk * 32 + g * 8);

    // O += P @ V  (B-frag: col=d=dt*16+c, k=key -> contiguous in Vt)
#pragma unroll
    for (int dt = 0; dt < 8; ++dt) {
#pragma unroll
      for (int kk = 0; kk < 2; ++kk) {
        ushort8 bv = *(const ushort8*)(Vt + (dt * 16 + c) * 72 + kk * 32 + g * 8);
        o_acc[dt] = mfma_bf16(a_p[kk], bv, o_acc[dt]);
      }
    }
  }

  // epilogue: O /= l, write to [B, L, H*D] bf16
  const int b = bh / 24, h = bh % 24;
  float rl[4];
#pragma unroll
  for (int j = 0; j < 4; ++j) rl[j] = 1.f / l_j[j];
#pragma unroll
  for (int dt = 0; dt < 8; ++dt) {
#pragma unroll
    for (int j = 0; j < 4; ++j) {
      int row = q0 + w * 16 + g * 4 + j;
      size_t idx = ((size_t)b * 2048 + row) * 3072 + h * 128 + dt * 16 + c;
      ob[idx] = f2bf(o_acc[dt][j] * rl[j]);
    }
  }
}

// ---------- launch ----------
extern "C" void kernel_launch(void* const* d_in, const int* in_sizes, int n_in,
                              void* d_out, int out_size, void* d_ws, size_t ws_size,
                              hipStream_t stream) {
  const float* x    = (const float*)d_in[0];
  const float* pe   = (const float*)d_in[1];
  const float* qkvw = (const float*)d_in[2];
  const float* pw   = (const float*)d_in[3];
  const float* pb   = (const float*)d_in[4];
  const float* qsc  = (const float*)d_in[5];
  const float* ksc  = (const float*)d_in[6];
  float* out = (float*)d_out;

  // workspace layout (bytes)
  char* p = (char*)d_ws;
  ushort_t* x_bf  = (ushort_t*)(p + 0);          // 25,165,824
  ushort_t* o_bf  = x_bf;                        // reuse: x dead after GEMM1
  ushort_t* qw_bf = (ushort_t*)(p + 25165824);   // 56,623,104
  ushort_t* pw_bf = (ushort_t*)(p + 81788928);   // 18,874,368
  ushort_t* qkv   = (ushort_t*)(p + 100663296);  // 75,497,472
  ushort_t* qh    = (ushort_t*)(p + 176160768);  // 25,165,824
  ushort_t* kh    = (ushort_t*)(p + 201326592);  // 25,165,824
  ushort_t* vh    = (ushort_t*)(p + 226492416);  // 25,165,824  (total ~251.7MB)

  cast_bf16<<<2048, 256, 0, stream>>>((const float4*)x,    (ushort4*)x_bf,  4096 * 3072 / 4);
  cast_bf16<<<2048, 256, 0, stream>>>((const float4*)qkvw, (ushort4*)qw_bf, 9216 * 3072 / 4);
  cast_bf16<<<2048, 256, 0, stream>>>((const float4*)pw,   (ushort4*)pw_bf, 3072 * 3072 / 4);

  gemm_bt<1, 0><<<dim3(72, 32), 256, 0, stream>>>(x_bf, qw_bf, nullptr, qkv, 4096, 9216, 3072);
  norm_rope<<<24576, 256, 0, stream>>>(qkv, pe, qsc, ksc, qh, kh, vh);
  attn_fwd<<<dim3(32, 48), 256, 0, stream>>>(qh, kh, vh, o_bf);
  gemm_bt<0, 1><<<dim3(24, 32), 256, 0, stream>>>(o_bf, pw_bf, pb, out, 4096, 3072, 3072);
}

// Round 2
// 806.558 us; speedup vs baseline: 1.1022x; 1.1022x over previous
//
#include <hip/hip_runtime.h>

typedef unsigned short ushort_t;
typedef unsigned short ushort8 __attribute__((ext_vector_type(8)));
typedef __bf16 bf16x8 __attribute__((ext_vector_type(8)));
typedef float f32x4 __attribute__((ext_vector_type(4)));

#define DEV __device__ __forceinline__

// ---------- helpers ----------
DEV ushort_t f2bf(float f) {
  unsigned u = __builtin_bit_cast(unsigned, f);
  u += 0x7FFFu + ((u >> 16) & 1u);   // RNE (no NaNs in this workload)
  return (ushort_t)(u >> 16);
}
DEV float bf2f(ushort_t u) {
  return __builtin_bit_cast(float, ((unsigned)u) << 16);
}
DEV void gload_lds16(const void* g, void* s) {
  __builtin_amdgcn_global_load_lds(
      (__attribute__((address_space(1))) void*)(size_t)g,
      (__attribute__((address_space(3))) void*)(size_t)s, 16, 0, 0);
}
DEV f32x4 mfma_bf16(ushort8 a, ushort8 b, f32x4 c) {
  return __builtin_amdgcn_mfma_f32_16x16x32_bf16(
      __builtin_bit_cast(bf16x8, a), __builtin_bit_cast(bf16x8, b), c, 0, 0, 0);
}

// ---------- 1) f32 -> bf16 cast ----------
__global__ void cast_bf16(const float4* __restrict__ in,
                          ushort4* __restrict__ out, int n4) {
  int stride = gridDim.x * blockDim.x;
  for (int i = blockIdx.x * blockDim.x + threadIdx.x; i < n4; i += stride) {
    float4 v = in[i];
    out[i] = make_ushort4(f2bf(v.x), f2bf(v.y), f2bf(v.z), f2bf(v.w));
  }
}

// ---------- 2) GEMM: C[m][n] = sum_k A[m][k] * Bw[n][k] (+bias) ----------
template <int OUT_BF16, int ADD_BIAS>
__global__ __launch_bounds__(256)
void gemm_bt(const ushort_t* __restrict__ A, const ushort_t* __restrict__ Bw,
             const float* __restrict__ bias, void* __restrict__ Cp,
             int M, int N, int K) {
  __shared__ ushort_t As[128 * 32];
  __shared__ ushort_t Bs[128 * 32];
  const int tid = threadIdx.x;
  const int w = tid >> 6, l = tid & 63;
  const int g = l >> 4, r = l & 15;
  const int wr = w >> 1, wc = w & 1;
  const int m0 = blockIdx.y * 128, n0 = blockIdx.x * 128;

  f32x4 acc[4][4];
#pragma unroll
  for (int i = 0; i < 4; ++i)
#pragma unroll
    for (int j = 0; j < 4; ++j) acc[i][j] = f32x4{0.f, 0.f, 0.f, 0.f};

  for (int k0 = 0; k0 < K; k0 += 32) {
    __syncthreads();
#pragma unroll
    for (int i = 0; i < 2; ++i) {
      int ch = w * 64 + i * 256 + l;
      int row = ch >> 2, off = (ch & 3) * 8;
      gload_lds16(A + (size_t)(m0 + row) * K + k0 + off,
                  As + (size_t)(w * 64 + i * 256) * 8);
      gload_lds16(Bw + (size_t)(n0 + row) * K + k0 + off,
                  Bs + (size_t)(w * 64 + i * 256) * 8);
    }
    __syncthreads();

    ushort8 av[4], bv[4];
#pragma unroll
    for (int mi = 0; mi < 4; ++mi)
      av[mi] = *(const ushort8*)(As + (wr * 64 + mi * 16 + r) * 32 + g * 8);
#pragma unroll
    for (int ni = 0; ni < 4; ++ni)
      bv[ni] = *(const ushort8*)(Bs + (wc * 64 + ni * 16 + r) * 32 + g * 8);
#pragma unroll
    for (int mi = 0; mi < 4; ++mi)
#pragma unroll
      for (int ni = 0; ni < 4; ++ni)
        acc[mi][ni] = mfma_bf16(av[mi], bv[ni], acc[mi][ni]);
  }

#pragma unroll
  for (int mi = 0; mi < 4; ++mi) {
#pragma unroll
    for (int ni = 0; ni < 4; ++ni) {
#pragma unroll
      for (int j = 0; j < 4; ++j) {
        int row = m0 + wr * 64 + mi * 16 + g * 4 + j;
        int col = n0 + wc * 64 + ni * 16 + r;
        float v = acc[mi][ni][j];
        if (ADD_BIAS) v += bias[col];
        if (OUT_BF16)
          ((ushort_t*)Cp)[(size_t)row * N + col] = f2bf(v);
        else
          ((float*)Cp)[(size_t)row * N + col] = v;
      }
    }
  }
}

// ---------- 3) RMSNorm + RoPE (Q,K row-major) + V transpose to [B,H,D,L] ----
// block = (64-token block, head). 4 waves.
__global__ __launch_bounds__(256)
void norm_rope(const ushort_t* __restrict__ qkv, const float* __restrict__ pe,
               const float* __restrict__ qs, const float* __restrict__ ksc,
               ushort_t* __restrict__ qb, ushort_t* __restrict__ kb,
               ushort_t* __restrict__ vtg) {
  __shared__ ushort_t Vt_lds[128 * 64];   // [d][token], XOR-swizzled
  const int tid = threadIdx.x;
  const int w = tid >> 6, lane = tid & 63;
  const int tb = blockIdx.x, h = blockIdx.y;
  const int bl0 = tb * 64;
  const int b = bl0 >> 11, l0 = bl0 & 2047;
  const int i2 = lane * 2;

  const float sq0 = qs[i2], sq1 = qs[i2 + 1];
  const float sk0 = ksc[i2], sk1 = ksc[i2 + 1];
  const float QSC = 0.12751744f;  // log2(e) / sqrt(128): softmax in base-2

  // Phase A: Q/K rmsnorm+rope, one token per wave-iteration (lane = d-pair)
  for (int t = 0; t < 16; ++t) {
    const int bl = bl0 + w * 16 + t;
    const float4 p4 = *(const float4*)(pe + (size_t)bl * 256 + lane * 4);
    const size_t src = (size_t)bl * 9216 + h * 128 + i2;
    const size_t dst = ((size_t)(b * 24 + h) * 2048 + (bl & 2047)) * 128 + i2;
    {  // Q
      unsigned u = *(const unsigned*)(qkv + src);
      float x0 = bf2f((ushort_t)(u & 0xFFFFu)), x1 = bf2f((ushort_t)(u >> 16));
      float ss = x0 * x0 + x1 * x1;
#pragma unroll
      for (int m = 32; m; m >>= 1) ss += __shfl_xor(ss, m, 64);
      float rr = rsqrtf(ss * (1.f / 128.f) + 1e-6f);
      float y0 = x0 * rr * sq0, y1 = x1 * rr * sq1;
      float o0 = (p4.x * y0 + p4.y * y1) * QSC;
      float o1 = (p4.z * y0 + p4.w * y1) * QSC;
      *(unsigned*)(qb + dst) = (unsigned)f2bf(o0) | ((unsigned)f2bf(o1) << 16);
    }
    {  // K
      unsigned u = *(const unsigned*)(qkv + src + 3072);
      float x0 = bf2f((ushort_t)(u & 0xFFFFu)), x1 = bf2f((ushort_t)(u >> 16));
      float ss = x0 * x0 + x1 * x1;
#pragma unroll
      for (int m = 32; m; m >>= 1) ss += __shfl_xor(ss, m, 64);
      float rr = rsqrtf(ss * (1.f / 128.f) + 1e-6f);
      float y0 = x0 * rr * sk0, y1 = x1 * rr * sk1;
      float o0 = p4.x * y0 + p4.y * y1;
      float o1 = p4.z * y0 + p4.w * y1;
      *(unsigned*)(kb + dst) = (unsigned)f2bf(o0) | ((unsigned)f2bf(o1) << 16);
    }
  }

  // Phase B: V -> LDS transposed. lane = token, wave w covers d-octets w*4..w*4+3
  {
    const ushort_t* vsrc = qkv + (size_t)(bl0 + lane) * 9216 + 6144 + h * 128;
#pragma unroll
    for (int i = 0; i < 4; ++i) {
      int oct = w * 4 + i;
      ushort8 vv = *(const ushort8*)(vsrc + oct * 8);
#pragma unroll
      for (int j = 0; j < 8; ++j) {
        int d = oct * 8 + j;                       // d&7 == j
        int ba = (d * 128 + lane * 2) ^ (j << 4);  // banks: (lane>>1)^... full spread
        *(ushort_t*)((char*)Vt_lds + ba) = vv[j];
      }
    }
  }
  __syncthreads();

  // Phase C: write V^T rows coalesced to global [B,H,D,L]
  {
    const int d = tid >> 1, half = tid & 1;
    ushort_t* orow = vtg + ((size_t)(b * 24 + h) * 128 + d) * 2048 + l0 + half * 32;
#pragma unroll
    for (int q = 0; q < 4; ++q) {
      int lb = d * 128 + half * 64 + q * 16;
      ushort8 vv = *(const ushort8*)((char*)Vt_lds + (lb ^ ((d & 7) << 4)));
      *(ushort8*)(orow + q * 8) = vv;
    }
  }
}

// ---------- 4) flash attention: 64 q-rows x one (b,h) per block ----------
// K and V^T staged via global_load_lds, linear LDS + pre-swizzled source (m173).
__global__ __launch_bounds__(256)
void attn_fwd(const ushort_t* __restrict__ qb, const ushort_t* __restrict__ kb,
              const ushort_t* __restrict__ vt, ushort_t* __restrict__ ob) {
  __shared__ ushort_t Ks[64 * 128];    // [key][d], phys = logical ^ ((key&7)<<4)
  __shared__ ushort_t Vts[128 * 64];   // [d][key], phys = logical ^ ((d&7)<<4)
  __shared__ ushort_t Ps[4][16 * 64];  // per-wave P, phys = logical ^ ((row&7)<<4)
  const int tid = threadIdx.x;
  const int w = tid >> 6, l = tid & 63;
  const int g = l >> 4, c = l & 15;
  const int bh = blockIdx.y;
  const int q0 = blockIdx.x * 64;

  const ushort_t* qrow = qb + ((size_t)bh * 2048 + q0 + w * 16 + c) * 128;
  ushort8 a_q[4];
#pragma unroll
  for (int dc = 0; dc < 4; ++dc)
    a_q[dc] = *(const ushort8*)(qrow + dc * 32 + g * 8);

  float m_j[4], l_j[4];
#pragma unroll
  for (int j = 0; j < 4; ++j) { m_j[j] = -3.4e38f; l_j[j] = 0.f; }
  f32x4 o_acc[8];
#pragma unroll
  for (int dt = 0; dt < 8; ++dt) o_acc[dt] = f32x4{0.f, 0.f, 0.f, 0.f};

  const ushort_t* kbase = kb + (size_t)bh * 2048 * 128;
  const ushort_t* vbase = vt + (size_t)bh * 128 * 2048;

  for (int kt = 0; kt < 2048; kt += 64) {
    __syncthreads();
    // stage K [64][128] and V^T [128][64]: 4 calls each per wave, 16B/lane
#pragma unroll
    for (int i = 0; i < 4; ++i) {
      int p0 = w * 256 + i * 64;
      int p = p0 + l;
      int krow = p >> 4, kch = (p & 15) ^ (krow & 7);
      gload_lds16(kbase + (size_t)(kt + krow) * 128 + kch * 8, Ks + p0 * 8);
      int vrow = p >> 3, vch = (p & 7) ^ (vrow & 7);
      gload_lds16(vbase + (size_t)vrow * 2048 + kt + vch * 8, Vts + p0 * 8);
    }
    __syncthreads();

    // S = Q K^T
    f32x4 sf[4];
#pragma unroll
    for (int kg = 0; kg < 4; ++kg) {
      f32x4 acc = f32x4{0.f, 0.f, 0.f, 0.f};
      int key = kg * 16 + c;
#pragma unroll
      for (int dc = 0; dc < 4; ++dc) {
        int lb = key * 256 + dc * 64 + g * 16;
        ushort8 bv = *(const ushort8*)((char*)Ks + (lb ^ ((key & 7) << 4)));
        acc = mfma_bf16(a_q[dc], bv, acc);
      }
      sf[kg] = acc;
    }

    // online softmax (base-2), defer-max THR=8
    float fs[4];
#pragma unroll
    for (int j = 0; j < 4; ++j) {
      float v = fmaxf(fmaxf(sf[0][j], sf[1][j]), fmaxf(sf[2][j], sf[3][j]));
      v = fmaxf(v, __shfl_xor(v, 1, 64));
      v = fmaxf(v, __shfl_xor(v, 2, 64));
      v = fmaxf(v, __shfl_xor(v, 4, 64));
      v = fmaxf(v, __shfl_xor(v, 8, 64));
      const bool stable = __all(v <= m_j[j] + 8.f);
      float mn = stable ? m_j[j] : fmaxf(m_j[j], v);
      fs[j] = stable ? 1.f : exp2f(m_j[j] - mn);
      m_j[j] = mn;
      float rs = 0.f;
#pragma unroll
      for (int kg = 0; kg < 4; ++kg) {
        float p = exp2f(sf[kg][j] - mn);
        sf[kg][j] = p;
        rs += p;
      }
      rs += __shfl_xor(rs, 1, 64);
      rs += __shfl_xor(rs, 2, 64);
      rs += __shfl_xor(rs, 4, 64);
      rs += __shfl_xor(rs, 8, 64);
      l_j[j] = l_j[j] * fs[j] + rs;
      if (!stable) {
#pragma unroll
        for (int dt = 0; dt < 8; ++dt) o_acc[dt][j] *= fs[j];
      }
    }

    // P (D-frag) -> LDS (swizzled) -> A-frags
    ushort_t* Pw = Ps[w];
#pragma unroll
    for (int kg = 0; kg < 4; ++kg)
#pragma unroll
      for (int j = 0; j < 4; ++j) {
        int rowl = g * 4 + j;
        int lb = rowl * 128 + (kg * 16 + c) * 2;
        *(ushort_t*)((char*)Pw + (lb ^ ((rowl & 7) << 4))) = f2bf(sf[kg][j]);
      }
    ushort8 a_p[2];
#pragma unroll
    for (int kk = 0; kk < 2; ++kk) {
      int lb = c * 128 + kk * 64 + g * 16;
      a_p[kk] = *(const ushort8*)((char*)Pw + (lb ^ ((c & 7) << 4)));
    }

    // O += P @ V  (B-frag from V^T: col d, k = key)
#pragma unroll
    for (int dt = 0; dt < 8; ++dt) {
#pragma unroll
      for (int kk = 0; kk < 2; ++kk) {
        int dcol = dt * 16 + c;
        int lb = dcol * 128 + kk * 64 + g * 16;
        ushort8 bv = *(const ushort8*)((char*)Vts + (lb ^ ((dcol & 7) << 4)));
        o_acc[dt] = mfma_bf16(a_p[kk], bv, o_acc[dt]);
      }
    }
  }

  // epilogue
  const int b = bh / 24, h = bh % 24;
  float rl[4];
#pragma unroll
  for (int j = 0; j < 4; ++j) rl[j] = 1.f / l_j[j];
#pragma unroll
  for (int dt = 0; dt < 8; ++dt) {
#pragma unroll
    for (int j = 0; j < 4; ++j) {
      int row = q0 + w * 16 + g * 4 + j;
      size_t idx = ((size_t)b * 2048 + row) * 3072 + h * 128 + dt * 16 + c;
      ob[idx] = f2bf(o_acc[dt][j] * rl[j]);
    }
  }
}

// ---------- launch ----------
extern "C" void kernel_launch(void* const* d_in, const int* in_sizes, int n_in,
                              void* d_out, int out_size, void* d_ws, size_t ws_size,
                              hipStream_t stream) {
  const float* x    = (const float*)d_in[0];
  const float* pe   = (const float*)d_in[1];
  const float* qkvw = (const float*)d_in[2];
  const float* pw   = (const float*)d_in[3];
  const float* pb   = (const float*)d_in[4];
  const float* qsc  = (const float*)d_in[5];
  const float* ksc  = (const float*)d_in[6];
  float* out = (float*)d_out;

  char* p = (char*)d_ws;
  ushort_t* x_bf  = (ushort_t*)(p + 0);          // 25,165,824
  ushort_t* o_bf  = x_bf;                        // reuse: x dead after GEMM1
  ushort_t* qw_bf = (ushort_t*)(p + 25165824);   // 56,623,104
  ushort_t* pw_bf = (ushort_t*)(p + 81788928);   // 18,874,368
  ushort_t* qkv   = (ushort_t*)(p + 100663296);  // 75,497,472
  ushort_t* qh    = (ushort_t*)(p + 176160768);  // 25,165,824
  ushort_t* kh    = (ushort_t*)(p + 201326592);  // 25,165,824
  ushort_t* vtg   = (ushort_t*)(p + 226492416);  // 25,165,824 (V^T [B,H,D,L])

  cast_bf16<<<2048, 256, 0, stream>>>((const float4*)x,    (ushort4*)x_bf,  4096 * 3072 / 4);
  cast_bf16<<<2048, 256, 0, stream>>>((const float4*)qkvw, (ushort4*)qw_bf, 9216 * 3072 / 4);
  cast_bf16<<<2048, 256, 0, stream>>>((const float4*)pw,   (ushort4*)pw_bf, 3072 * 3072 / 4);

  gemm_bt<1, 0><<<dim3(72, 32), 256, 0, stream>>>(x_bf, qw_bf, nullptr, qkv, 4096, 9216, 3072);
  norm_rope<<<dim3(64, 24), 256, 0, stream>>>(qkv, pe, qsc, ksc, qh, kh, vtg);
  attn_fwd<<<dim3(32, 48), 256, 0, stream>>>(qh, kh, vtg, o_bf);
  gemm_bt<0, 1><<<dim3(24, 32), 256, 0, stream>>>(o_bf, pw_bf, pb, out, 4096, 3072, 3072);
}

// Round 4
// 651.166 us; speedup vs baseline: 1.3653x; 1.2386x over previous
//
#include <hip/hip_runtime.h>

typedef unsigned short ushort_t;
typedef unsigned short ushort8 __attribute__((ext_vector_type(8)));
typedef __bf16 bf16x8 __attribute__((ext_vector_type(8)));
typedef float f32x4 __attribute__((ext_vector_type(4)));
typedef float f32x16 __attribute__((ext_vector_type(16)));
typedef unsigned uint32x4 __attribute__((ext_vector_type(4)));

#define DEV __device__ __forceinline__

// ---------- helpers ----------
DEV ushort_t f2bf(float f) {
  unsigned u = __builtin_bit_cast(unsigned, f);
  u += 0x7FFFu + ((u >> 16) & 1u);   // RNE (no NaNs in this workload)
  return (ushort_t)(u >> 16);
}
DEV float bf2f(ushort_t u) {
  return __builtin_bit_cast(float, ((unsigned)u) << 16);
}
DEV void gload_lds16(const void* g, void* s) {
  __builtin_amdgcn_global_load_lds(
      (__attribute__((address_space(1))) void*)(size_t)g,
      (__attribute__((address_space(3))) void*)(size_t)s, 16, 0, 0);
}
DEV f32x4 mfma_bf16(ushort8 a, ushort8 b, f32x4 c) {
  return __builtin_amdgcn_mfma_f32_16x16x32_bf16(
      __builtin_bit_cast(bf16x8, a), __builtin_bit_cast(bf16x8, b), c, 0, 0, 0);
}
DEV f32x16 mfma32(ushort8 a, ushort8 b, f32x16 c) {
  return __builtin_amdgcn_mfma_f32_32x32x16_bf16(
      __builtin_bit_cast(bf16x8, a), __builtin_bit_cast(bf16x8, b), c, 0, 0, 0);
}
DEV f32x16 zero16() {
  f32x16 z;
#pragma unroll
  for (int i = 0; i < 16; ++i) z[i] = 0.f;
  return z;
}
DEV unsigned cvtpk(float lo, float hi2) {  // u32 = {bf16(hi2), bf16(lo)}
  unsigned r;
  asm("v_cvt_pk_bf16_f32 %0, %1, %2" : "=v"(r) : "v"(lo), "v"(hi2));
  return r;
}
// x'[l] = l<32 ? x[l] : y[l-32];  y'[l] = l<32 ? x[l+32] : y[l]
DEV void swap32(unsigned &x, unsigned &y) {
#if __has_builtin(__builtin_amdgcn_permlane32_swap)
  auto t = __builtin_amdgcn_permlane32_swap(x, y, false, false);
  x = (unsigned)t[0];
  y = (unsigned)t[1];
#else
  unsigned xs = (unsigned)__shfl_xor((int)x, 32, 64);
  unsigned ys = (unsigned)__shfl_xor((int)y, 32, 64);
  bool h = (threadIdx.x & 63) >= 32;
  unsigned nx = h ? ys : x;
  unsigned ny = h ? y : xs;
  x = nx; y = ny;
#endif
}

// ---------- 1) f32 -> bf16 cast ----------
__global__ void cast_bf16(const float4* __restrict__ in,
                          ushort4* __restrict__ out, int n4) {
  int stride = gridDim.x * blockDim.x;
  for (int i = blockIdx.x * blockDim.x + threadIdx.x; i < n4; i += stride) {
    float4 v = in[i];
    out[i] = make_ushort4(f2bf(v.x), f2bf(v.y), f2bf(v.z), f2bf(v.w));
  }
}

// ---------- 2) GEMM: C[m][n] = sum_k A[m][k] * Bw[n][k] (+bias) ----------
template <int OUT_BF16, int ADD_BIAS>
__global__ __launch_bounds__(256)
void gemm_bt(const ushort_t* __restrict__ A, const ushort_t* __restrict__ Bw,
             const float* __restrict__ bias, void* __restrict__ Cp,
             int M, int N, int K) {
  __shared__ ushort_t As[128 * 32];
  __shared__ ushort_t Bs[128 * 32];
  const int tid = threadIdx.x;
  const int w = tid >> 6, l = tid & 63;
  const int g = l >> 4, r = l & 15;
  const int wr = w >> 1, wc = w & 1;
  const int m0 = blockIdx.y * 128, n0 = blockIdx.x * 128;

  f32x4 acc[4][4];
#pragma unroll
  for (int i = 0; i < 4; ++i)
#pragma unroll
    for (int j = 0; j < 4; ++j) acc[i][j] = f32x4{0.f, 0.f, 0.f, 0.f};

  for (int k0 = 0; k0 < K; k0 += 32) {
    __syncthreads();
#pragma unroll
    for (int i = 0; i < 2; ++i) {
      int ch = w * 64 + i * 256 + l;
      int row = ch >> 2, off = (ch & 3) * 8;
      gload_lds16(A + (size_t)(m0 + row) * K + k0 + off,
                  As + (size_t)(w * 64 + i * 256) * 8);
      gload_lds16(Bw + (size_t)(n0 + row) * K + k0 + off,
                  Bs + (size_t)(w * 64 + i * 256) * 8);
    }
    __syncthreads();

    ushort8 av[4], bv[4];
#pragma unroll
    for (int mi = 0; mi < 4; ++mi)
      av[mi] = *(const ushort8*)(As + (wr * 64 + mi * 16 + r) * 32 + g * 8);
#pragma unroll
    for (int ni = 0; ni < 4; ++ni)
      bv[ni] = *(const ushort8*)(Bs + (wc * 64 + ni * 16 + r) * 32 + g * 8);
#pragma unroll
    for (int mi = 0; mi < 4; ++mi)
#pragma unroll
      for (int ni = 0; ni < 4; ++ni)
        acc[mi][ni] = mfma_bf16(av[mi], bv[ni], acc[mi][ni]);
  }

#pragma unroll
  for (int mi = 0; mi < 4; ++mi) {
#pragma unroll
    for (int ni = 0; ni < 4; ++ni) {
#pragma unroll
      for (int j = 0; j < 4; ++j) {
        int row = m0 + wr * 64 + mi * 16 + g * 4 + j;
        int col = n0 + wc * 64 + ni * 16 + r;
        float v = acc[mi][ni][j];
        if (ADD_BIAS) v += bias[col];
        if (OUT_BF16)
          ((ushort_t*)Cp)[(size_t)row * N + col] = f2bf(v);
        else
          ((float*)Cp)[(size_t)row * N + col] = v;
      }
    }
  }
}

// ---------- 3) RMSNorm + RoPE (Q,K row-major) + V transpose to [B,H,D,L] ----
__global__ __launch_bounds__(256)
void norm_rope(const ushort_t* __restrict__ qkv, const float* __restrict__ pe,
               const float* __restrict__ qs, const float* __restrict__ ksc,
               ushort_t* __restrict__ qb, ushort_t* __restrict__ kb,
               ushort_t* __restrict__ vtg) {
  __shared__ ushort_t Vt_lds[128 * 64];   // [d][token], XOR-swizzled
  const int tid = threadIdx.x;
  const int w = tid >> 6, lane = tid & 63;
  const int tb = blockIdx.x, h = blockIdx.y;
  const int bl0 = tb * 64;
  const int b = bl0 >> 11, l0 = bl0 & 2047;
  const int i2 = lane * 2;

  const float sq0 = qs[i2], sq1 = qs[i2 + 1];
  const float sk0 = ksc[i2], sk1 = ksc[i2 + 1];
  const float QSC = 0.12751744f;  // log2(e) / sqrt(128): softmax in base-2

  for (int t = 0; t < 16; ++t) {
    const int bl = bl0 + w * 16 + t;
    const float4 p4 = *(const float4*)(pe + (size_t)bl * 256 + lane * 4);
    const size_t src = (size_t)bl * 9216 + h * 128 + i2;
    const size_t dst = ((size_t)(b * 24 + h) * 2048 + (bl & 2047)) * 128 + i2;
    {  // Q
      unsigned u = *(const unsigned*)(qkv + src);
      float x0 = bf2f((ushort_t)(u & 0xFFFFu)), x1 = bf2f((ushort_t)(u >> 16));
      float ss = x0 * x0 + x1 * x1;
#pragma unroll
      for (int mm = 32; mm; mm >>= 1) ss += __shfl_xor(ss, mm, 64);
      float rr = rsqrtf(ss * (1.f / 128.f) + 1e-6f);
      float y0 = x0 * rr * sq0, y1 = x1 * rr * sq1;
      float o0 = (p4.x * y0 + p4.y * y1) * QSC;
      float o1 = (p4.z * y0 + p4.w * y1) * QSC;
      *(unsigned*)(qb + dst) = (unsigned)f2bf(o0) | ((unsigned)f2bf(o1) << 16);
    }
    {  // K
      unsigned u = *(const unsigned*)(qkv + src + 3072);
      float x0 = bf2f((ushort_t)(u & 0xFFFFu)), x1 = bf2f((ushort_t)(u >> 16));
      float ss = x0 * x0 + x1 * x1;
#pragma unroll
      for (int mm = 32; mm; mm >>= 1) ss += __shfl_xor(ss, mm, 64);
      float rr = rsqrtf(ss * (1.f / 128.f) + 1e-6f);
      float y0 = x0 * rr * sk0, y1 = x1 * rr * sk1;
      float o0 = p4.x * y0 + p4.y * y1;
      float o1 = p4.z * y0 + p4.w * y1;
      *(unsigned*)(kb + dst) = (unsigned)f2bf(o0) | ((unsigned)f2bf(o1) << 16);
    }
  }

  {  // V -> LDS transposed
    const ushort_t* vsrc = qkv + (size_t)(bl0 + lane) * 9216 + 6144 + h * 128;
#pragma unroll
    for (int i = 0; i < 4; ++i) {
      int oct = w * 4 + i;
      ushort8 vv = *(const ushort8*)(vsrc + oct * 8);
#pragma unroll
      for (int j = 0; j < 8; ++j) {
        int d = oct * 8 + j;
        int ba = (d * 128 + lane * 2) ^ (j << 4);
        *(ushort_t*)((char*)Vt_lds + ba) = vv[j];
      }
    }
  }
  __syncthreads();

  {  // coalesced V^T rows to global [B,H,D,L]
    const int d = tid >> 1, half = tid & 1;
    ushort_t* orow = vtg + ((size_t)(b * 24 + h) * 128 + d) * 2048 + l0 + half * 32;
#pragma unroll
    for (int q = 0; q < 4; ++q) {
      int lb = d * 128 + half * 64 + q * 16;
      ushort8 vv = *(const ushort8*)((char*)Vt_lds + (lb ^ ((d & 7) << 4)));
      *(ushort8*)(orow + q * 8) = vv;
    }
  }
}

// ---------- 4) flash attention: swapped 32x32 structure ----------
// block = 4 waves x 32 q-rows = 128 q; S^T = mfma32(K, Q): lane (c,hi) holds
// S[q=c][key=crow(r,hi)], crow = (r&3)+8*(r>>2)+4*hi. Softmax max m is kept
// WAVE-UNIFORM (defer-max THR=8, full-wave reduce on rescale) so the O
// rescale is valid in O's different lane layout (O row = crow(r,hi), col=d).
// Final 1/l redistributed via bpermute. P -> PV A-operand via cvt_pk +
// permlane32_swap (T12). K/V^T staged via global_load_lds, linear LDS dest +
// pre-swizzled global source (K: 4-bit chunk XOR, V: 3-bit).
__global__ __launch_bounds__(256, 2)
void attn_fwd(const ushort_t* __restrict__ qb, const ushort_t* __restrict__ kb,
              const ushort_t* __restrict__ vt, ushort_t* __restrict__ ob) {
  __shared__ ushort_t Ks[64 * 128];    // [key][d],  phys chunk = log ^ (key&15)
  __shared__ ushort_t Vts[128 * 64];   // [d][key],  phys chunk = log ^ (d&7)
  const int tid = threadIdx.x;
  const int w = tid >> 6, l = tid & 63;
  const int c = l & 31, hi = l >> 5;
  const int bh = blockIdx.y;
  const int q0 = blockIdx.x * 128 + w * 32;

  // Q B-frags: lane holds Q[q0+c][k = s*16 + hi*8 .. +8]
  const ushort_t* qrow = qb + ((size_t)bh * 2048 + q0 + c) * 128;
  ushort8 qf[8];
#pragma unroll
  for (int s = 0; s < 8; ++s)
    qf[s] = *(const ushort8*)(qrow + s * 16 + hi * 8);

  f32x16 o[4];
#pragma unroll
  for (int dt = 0; dt < 4; ++dt) o[dt] = zero16();
  float m = -1e30f, lp = 0.f;   // m is wave-uniform; lp is row-c partial sum

  const ushort_t* kbase = kb + (size_t)bh * 2048 * 128;
  const ushort_t* vbase = vt + (size_t)bh * 128 * 2048;

  for (int kt = 0; kt < 2048; kt += 64) {
    __syncthreads();
#pragma unroll
    for (int i = 0; i < 4; ++i) {
      int u = w * 256 + i * 64 + l;
      int kr = u >> 4, kc = (u & 15) ^ (kr & 15);
      gload_lds16(kbase + (size_t)(kt + kr) * 128 + kc * 8,
                  Ks + (w * 256 + i * 64) * 8);
      int vr = u >> 3, vc = (u & 7) ^ (vr & 7);
      gload_lds16(vbase + (size_t)vr * 2048 + kt + vc * 8,
                  Vts + (w * 256 + i * 64) * 8);
    }
    __syncthreads();

    // S^T = K · Q^T : two 32-key tiles, 8 d-steps of k=16
    f32x16 s0 = zero16(), s1 = zero16();
#pragma unroll
    for (int ds = 0; ds < 8; ++ds) {
      int ch = (2 * ds + hi) ^ (c & 15);
      ushort8 k0 = *(const ushort8*)(Ks + c * 128 + ch * 8);
      ushort8 k1 = *(const ushort8*)(Ks + (32 + c) * 128 + ch * 8);
      s0 = mfma32(k0, qf[ds], s0);
      s1 = mfma32(k1, qf[ds], s1);
    }

    // online softmax (base-2), wave-uniform max, defer THR=8
    float p[32];
#pragma unroll
    for (int r = 0; r < 16; ++r) { p[r] = s0[r]; p[16 + r] = s1[r]; }
    float pmax = p[0];
#pragma unroll
    for (int r = 1; r < 32; ++r) pmax = fmaxf(pmax, p[r]);
    if (!__all(pmax <= m + 8.f)) {
      float wm = pmax;
#pragma unroll
      for (int d = 1; d < 64; d <<= 1) wm = fmaxf(wm, __shfl_xor(wm, d, 64));
      float mn = fmaxf(m, wm);        // wave-uniform new max
      float fs = exp2f(m - mn);       // wave-uniform -> layout-independent
      m = mn;
      lp *= fs;
#pragma unroll
      for (int dt = 0; dt < 4; ++dt)
#pragma unroll
        for (int e = 0; e < 16; ++e) o[dt][e] *= fs;
    }
    float rs = 0.f;
#pragma unroll
    for (int r = 0; r < 32; ++r) { p[r] = exp2f(p[r] - m); rs += p[r]; }
    lp += rs;

    // P -> A-frag words: per 16-key step: 4 cvt_pk + 2 permlane32_swap
    uint32x4 pk[4];
#pragma unroll
    for (int ks = 0; ks < 4; ++ks) {
      unsigned a0 = cvtpk(p[ks * 8 + 0], p[ks * 8 + 1]);
      unsigned a1 = cvtpk(p[ks * 8 + 2], p[ks * 8 + 3]);
      unsigned a2 = cvtpk(p[ks * 8 + 4], p[ks * 8 + 5]);
      unsigned a3 = cvtpk(p[ks * 8 + 6], p[ks * 8 + 7]);
      swap32(a0, a2);
      swap32(a1, a3);
      pk[ks] = uint32x4{a0, a1, a2, a3};
    }

    // O += P · V : A = P-frag (regs), B = V-frag from V^T LDS
#pragma unroll
    for (int dt = 0; dt < 4; ++dt) {
#pragma unroll
      for (int ks = 0; ks < 4; ++ks) {
        int ch = (2 * ks + hi) ^ (c & 7);
        ushort8 vf = *(const ushort8*)(Vts + (32 * dt + c) * 64 + ch * 8);
        o[dt] = mfma32(__builtin_bit_cast(ushort8, pk[ks]), vf, o[dt]);
      }
    }
  }

  // epilogue: lr lives at lane q (row c); O rows are crow(r,hi) -> bpermute
  float lr = lp + __shfl_xor(lp, 32, 64);
  float rl = 1.f / lr;
  const int b = bh / 24, h = bh % 24;
  ushort_t* obase = ob + ((size_t)b * 2048 + q0) * 3072 + h * 128 + c;
#pragma unroll
  for (int r = 0; r < 16; ++r) {
    int q = (r & 3) + 8 * (r >> 2) + 4 * hi;
    float os = __shfl(rl, q, 64);   // denominator of row q
#pragma unroll
    for (int dt = 0; dt < 4; ++dt)
      obase[(size_t)q * 3072 + dt * 32] = f2bf(o[dt][r] * os);
  }
}

// ---------- launch ----------
extern "C" void kernel_launch(void* const* d_in, const int* in_sizes, int n_in,
                              void* d_out, int out_size, void* d_ws, size_t ws_size,
                              hipStream_t stream) {
  const float* x    = (const float*)d_in[0];
  const float* pe   = (const float*)d_in[1];
  const float* qkvw = (const float*)d_in[2];
  const float* pw   = (const float*)d_in[3];
  const float* pb   = (const float*)d_in[4];
  const float* qsc  = (const float*)d_in[5];
  const float* ksc  = (const float*)d_in[6];
  float* out = (float*)d_out;

  char* p = (char*)d_ws;
  ushort_t* x_bf  = (ushort_t*)(p + 0);          // 25,165,824
  ushort_t* o_bf  = x_bf;                        // reuse: x dead after GEMM1
  ushort_t* qw_bf = (ushort_t*)(p + 25165824);   // 56,623,104
  ushort_t* pw_bf = (ushort_t*)(p + 81788928);   // 18,874,368
  ushort_t* qkv   = (ushort_t*)(p + 100663296);  // 75,497,472
  ushort_t* qh    = (ushort_t*)(p + 176160768);  // 25,165,824
  ushort_t* kh    = (ushort_t*)(p + 201326592);  // 25,165,824
  ushort_t* vtg   = (ushort_t*)(p + 226492416);  // 25,165,824 (V^T [B,H,D,L])

  cast_bf16<<<2048, 256, 0, stream>>>((const float4*)x,    (ushort4*)x_bf,  4096 * 3072 / 4);
  cast_bf16<<<2048, 256, 0, stream>>>((const float4*)qkvw, (ushort4*)qw_bf, 9216 * 3072 / 4);
  cast_bf16<<<2048, 256, 0, stream>>>((const float4*)pw,   (ushort4*)pw_bf, 3072 * 3072 / 4);

  gemm_bt<1, 0><<<dim3(72, 32), 256, 0, stream>>>(x_bf, qw_bf, nullptr, qkv, 4096, 9216, 3072);
  norm_rope<<<dim3(64, 24), 256, 0, stream>>>(qkv, pe, qsc, ksc, qh, kh, vtg);
  attn_fwd<<<dim3(16, 48), 256, 0, stream>>>(qh, kh, vtg, o_bf);
  gemm_bt<0, 1><<<dim3(24, 32), 256, 0, stream>>>(o_bf, pw_bf, pb, out, 4096, 3072, 3072);
}

// Round 5
// 562.391 us; speedup vs baseline: 1.5808x; 1.1579x over previous
//
#include <hip/hip_runtime.h>

typedef unsigned short ushort_t;
typedef unsigned short ushort8 __attribute__((ext_vector_type(8)));
typedef __bf16 bf16x8 __attribute__((ext_vector_type(8)));
typedef float f32x4 __attribute__((ext_vector_type(4)));
typedef float f32x16 __attribute__((ext_vector_type(16)));
typedef unsigned uint32x4 __attribute__((ext_vector_type(4)));

#define DEV __device__ __forceinline__

// ---------- helpers ----------
DEV ushort_t f2bf(float f) {
  unsigned u = __builtin_bit_cast(unsigned, f);
  u += 0x7FFFu + ((u >> 16) & 1u);   // RNE (no NaNs in this workload)
  return (ushort_t)(u >> 16);
}
DEV float bf2f(ushort_t u) {
  return __builtin_bit_cast(float, ((unsigned)u) << 16);
}
DEV void gload_lds16(const void* g, void* s) {
  __builtin_amdgcn_global_load_lds(
      (__attribute__((address_space(1))) void*)(size_t)g,
      (__attribute__((address_space(3))) void*)(size_t)s, 16, 0, 0);
}
DEV f32x4 mfma_bf16(ushort8 a, ushort8 b, f32x4 c) {
  return __builtin_amdgcn_mfma_f32_16x16x32_bf16(
      __builtin_bit_cast(bf16x8, a), __builtin_bit_cast(bf16x8, b), c, 0, 0, 0);
}
DEV f32x16 mfma32(ushort8 a, ushort8 b, f32x16 c) {
  return __builtin_amdgcn_mfma_f32_32x32x16_bf16(
      __builtin_bit_cast(bf16x8, a), __builtin_bit_cast(bf16x8, b), c, 0, 0, 0);
}
DEV f32x16 zero16() {
  f32x16 z;
#pragma unroll
  for (int i = 0; i < 16; ++i) z[i] = 0.f;
  return z;
}
DEV unsigned cvtpk(float lo, float hi2) {  // u32 = {bf16(hi2), bf16(lo)}
  unsigned r;
  asm("v_cvt_pk_bf16_f32 %0, %1, %2" : "=v"(r) : "v"(lo), "v"(hi2));
  return r;
}
// x'[l] = l<32 ? x[l] : y[l-32];  y'[l] = l<32 ? x[l+32] : y[l]
DEV void swap32(unsigned &x, unsigned &y) {
#if __has_builtin(__builtin_amdgcn_permlane32_swap)
  auto t = __builtin_amdgcn_permlane32_swap(x, y, false, false);
  x = (unsigned)t[0];
  y = (unsigned)t[1];
#else
  unsigned xs = (unsigned)__shfl_xor((int)x, 32, 64);
  unsigned ys = (unsigned)__shfl_xor((int)y, 32, 64);
  bool h = (threadIdx.x & 63) >= 32;
  unsigned nx = h ? ys : x;
  unsigned ny = h ? y : xs;
  x = nx; y = ny;
#endif
}
DEV void barx() {  // raw barrier, no vmcnt drain; compiler memory fence
  asm volatile("" ::: "memory");
  __builtin_amdgcn_s_barrier();
  asm volatile("" ::: "memory");
}
#define GATE_VM2 asm volatile("s_waitcnt vmcnt(2)" ::: "memory")
#define GATE_VM8 asm volatile("s_waitcnt vmcnt(8)" ::: "memory")

// ---------- 1) f32 -> bf16 cast ----------
__global__ void cast_bf16(const float4* __restrict__ in,
                          ushort4* __restrict__ out, int n4) {
  int stride = gridDim.x * blockDim.x;
  for (int i = blockIdx.x * blockDim.x + threadIdx.x; i < n4; i += stride) {
    float4 v = in[i];
    out[i] = make_ushort4(f2bf(v.x), f2bf(v.y), f2bf(v.z), f2bf(v.w));
  }
}

// ---------- 2) GEMM 256x256 8-phase (T2+T3+T4+T5): C = A * Bw^T (+bias) ----
// 8 waves (2M x 4N), BK=64, 2 K-tiles per iteration, double-buffered LDS.
// LDS chunk swizzle: phys_chunk = chunk ^ (row&7)  (both-sides, rule #21).
// Staging order per K-tile: [A0,A2,B0,B1,B2,B3,A1,A3]; gates: vmcnt(8) at
// phase-2 end (drains old A1,A3), vmcnt(2) at phase-4 end (drains first-6 of
// the tile consumed next half). Never drains to 0 in the main loop (T4).
template <int OUT_BF16, int ADD_BIAS>
__global__ __launch_bounds__(512, 2)
void gemm256(const ushort_t* __restrict__ A, const ushort_t* __restrict__ Bw,
             const float* __restrict__ bias, void* __restrict__ Cp,
             int M, int N, int K) {
  __shared__ ushort_t As[2][256 * 64];
  __shared__ ushort_t Bs[2][256 * 64];
  const int tid = threadIdx.x;
  const int w = tid >> 6, l = tid & 63;
  const int g = l >> 4, r = l & 15;
  const int wm = w >> 2, wn = w & 3;
  const int m0 = blockIdx.y * 256, n0 = blockIdx.x * 256;
  const int NT = K >> 6;    // number of 64-wide K tiles
  const int NI = NT >> 1;   // iterations (2 tiles each)

  // staging geometry: instr i covers rows [i*64, i*64+64), this lane -> chunk u
  int srow[4], soff[4];
#pragma unroll
  for (int i = 0; i < 4; ++i) {
    int u = i * 512 + tid;
    int row = u >> 3, pc = u & 7;
    srow[i] = row;
    soff[i] = (pc ^ (row & 7)) * 8;   // pre-swizzled source k-offset (elems)
  }

  auto stA = [&](int i, int t, int db) {
    gload_lds16(A + (size_t)(m0 + srow[i]) * K + t * 64 + soff[i],
                As[db] + (i * 512 + w * 64) * 8);
  };
  auto stB = [&](int i, int t, int db) {
    gload_lds16(Bw + (size_t)(n0 + srow[i]) * K + t * 64 + soff[i],
                Bs[db] + (i * 512 + w * 64) * 8);
  };
  auto rdA = [&](int db, int mi, int kk) -> ushort8 {
    int row = wm * 128 + mi * 16 + r;
    return *(const ushort8*)(As[db] + row * 64 + (((kk << 2) + g) ^ (r & 7)) * 8);
  };
  auto rdB = [&](int db, int ni, int kk) -> ushort8 {
    int col = wn * 64 + ni * 16 + r;
    return *(const ushort8*)(Bs[db] + col * 64 + (((kk << 2) + g) ^ (r & 7)) * 8);
  };

  f32x4 acc[8][4];
#pragma unroll
  for (int i = 0; i < 8; ++i)
#pragma unroll
    for (int j = 0; j < 4; ++j) acc[i][j] = f32x4{0.f, 0.f, 0.f, 0.f};

  ushort8 af[4][2], bf[4][2];

  // prologue: stage t0 -> buf0 in gate order, leave A1,A3 in flight
  stA(0, 0, 0); stA(2, 0, 0);
  stB(0, 0, 0); stB(1, 0, 0); stB(2, 0, 0); stB(3, 0, 0);
  stA(1, 0, 0); stA(3, 0, 0);
  GATE_VM2;
  barx();

  for (int it = 0; it < NI; ++it) {
#pragma unroll
    for (int half = 0; half < 2; ++half) {
      const int db = half;
      int ts = 2 * it + 1 + half;          // tile staged into buf db^1
      if (ts > NT - 1) ts = NT - 1;        // clamp (redundant, harmless)

      // ---- phase 1/5: reads A(m0-3) 8 + B(n0-1) 4; stage A0,A2,B0,B1
#pragma unroll
      for (int mi = 0; mi < 4; ++mi)
#pragma unroll
        for (int kk = 0; kk < 2; ++kk) af[mi][kk] = rdA(db, mi, kk);
#pragma unroll
      for (int ni = 0; ni < 2; ++ni)
#pragma unroll
        for (int kk = 0; kk < 2; ++kk) bf[ni][kk] = rdB(db, ni, kk);
      stA(0, ts, db ^ 1); stA(2, ts, db ^ 1);
      stB(0, ts, db ^ 1); stB(1, ts, db ^ 1);
      barx();
      __builtin_amdgcn_s_setprio(1);
#pragma unroll
      for (int mi = 0; mi < 4; ++mi)
#pragma unroll
        for (int ni = 0; ni < 2; ++ni)
#pragma unroll
          for (int kk = 0; kk < 2; ++kk)
            acc[mi][ni] = mfma_bf16(af[mi][kk], bf[ni][kk], acc[mi][ni]);
      __builtin_amdgcn_s_setprio(0);
      barx();

      // ---- phase 2/6: reads B(n2-3) 4; stage B2,B3,A1,A3; gate vmcnt(8)
#pragma unroll
      for (int ni = 2; ni < 4; ++ni)
#pragma unroll
        for (int kk = 0; kk < 2; ++kk) bf[ni][kk] = rdB(db, ni, kk);
      stB(2, ts, db ^ 1); stB(3, ts, db ^ 1);
      stA(1, ts, db ^ 1); stA(3, ts, db ^ 1);
      barx();
      __builtin_amdgcn_s_setprio(1);
#pragma unroll
      for (int mi = 0; mi < 4; ++mi)
#pragma unroll
        for (int ni = 2; ni < 4; ++ni)
#pragma unroll
          for (int kk = 0; kk < 2; ++kk)
            acc[mi][ni] = mfma_bf16(af[mi][kk], bf[ni][kk], acc[mi][ni]);
      __builtin_amdgcn_s_setprio(0);
      GATE_VM8;   // old tile's A1,A3 landed (needed by phase 3)
      barx();

      // ---- phase 3/7: reads A(m4-7) 8
#pragma unroll
      for (int mi = 0; mi < 4; ++mi)
#pragma unroll
        for (int kk = 0; kk < 2; ++kk) af[mi][kk] = rdA(db, mi + 4, kk);
      barx();
      __builtin_amdgcn_s_setprio(1);
#pragma unroll
      for (int mi = 0; mi < 4; ++mi)
#pragma unroll
        for (int ni = 0; ni < 2; ++ni)
#pragma unroll
          for (int kk = 0; kk < 2; ++kk)
            acc[mi + 4][ni] = mfma_bf16(af[mi][kk], bf[ni][kk], acc[mi + 4][ni]);
      __builtin_amdgcn_s_setprio(0);
      barx();

      // ---- phase 4/8: no reads; gate vmcnt(2)
      __builtin_amdgcn_s_setprio(1);
#pragma unroll
      for (int mi = 0; mi < 4; ++mi)
#pragma unroll
        for (int ni = 2; ni < 4; ++ni)
#pragma unroll
          for (int kk = 0; kk < 2; ++kk)
            acc[mi + 4][ni] = mfma_bf16(af[mi][kk], bf[ni][kk], acc[mi + 4][ni]);
      __builtin_amdgcn_s_setprio(0);
      GATE_VM2;   // next tile's {A0,A2,B0-B3} landed (needed next half ph1)
      barx();
    }
  }

  // epilogue: D row = 4g+j (M-dim), col = r (N-dim)
#pragma unroll
  for (int mi = 0; mi < 8; ++mi) {
#pragma unroll
    for (int ni = 0; ni < 4; ++ni) {
#pragma unroll
      for (int j = 0; j < 4; ++j) {
        int row = m0 + wm * 128 + mi * 16 + g * 4 + j;
        int col = n0 + wn * 64 + ni * 16 + r;
        float v = acc[mi][ni][j];
        if (ADD_BIAS) v += bias[col];
        if (OUT_BF16)
          ((ushort_t*)Cp)[(size_t)row * N + col] = f2bf(v);
        else
          ((float*)Cp)[(size_t)row * N + col] = v;
      }
    }
  }
}

// ---------- 3) RMSNorm + RoPE (Q,K row-major) + V transpose to [B,H,D,L] ----
__global__ __launch_bounds__(256)
void norm_rope(const ushort_t* __restrict__ qkv, const float* __restrict__ pe,
               const float* __restrict__ qs, const float* __restrict__ ksc,
               ushort_t* __restrict__ qb, ushort_t* __restrict__ kb,
               ushort_t* __restrict__ vtg) {
  __shared__ ushort_t Vt_lds[128 * 64];   // [d][token], XOR-swizzled
  const int tid = threadIdx.x;
  const int w = tid >> 6, lane = tid & 63;
  const int tb = blockIdx.x, h = blockIdx.y;
  const int bl0 = tb * 64;
  const int b = bl0 >> 11, l0 = bl0 & 2047;
  const int i2 = lane * 2;

  const float sq0 = qs[i2], sq1 = qs[i2 + 1];
  const float sk0 = ksc[i2], sk1 = ksc[i2 + 1];
  const float QSC = 0.12751744f;  // log2(e) / sqrt(128): softmax in base-2

  for (int t = 0; t < 16; ++t) {
    const int bl = bl0 + w * 16 + t;
    const float4 p4 = *(const float4*)(pe + (size_t)bl * 256 + lane * 4);
    const size_t src = (size_t)bl * 9216 + h * 128 + i2;
    const size_t dst = ((size_t)(b * 24 + h) * 2048 + (bl & 2047)) * 128 + i2;
    {  // Q
      unsigned u = *(const unsigned*)(qkv + src);
      float x0 = bf2f((ushort_t)(u & 0xFFFFu)), x1 = bf2f((ushort_t)(u >> 16));
      float ss = x0 * x0 + x1 * x1;
#pragma unroll
      for (int mm = 32; mm; mm >>= 1) ss += __shfl_xor(ss, mm, 64);
      float rr = rsqrtf(ss * (1.f / 128.f) + 1e-6f);
      float y0 = x0 * rr * sq0, y1 = x1 * rr * sq1;
      float o0 = (p4.x * y0 + p4.y * y1) * QSC;
      float o1 = (p4.z * y0 + p4.w * y1) * QSC;
      *(unsigned*)(qb + dst) = (unsigned)f2bf(o0) | ((unsigned)f2bf(o1) << 16);
    }
    {  // K
      unsigned u = *(const unsigned*)(qkv + src + 3072);
      float x0 = bf2f((ushort_t)(u & 0xFFFFu)), x1 = bf2f((ushort_t)(u >> 16));
      float ss = x0 * x0 + x1 * x1;
#pragma unroll
      for (int mm = 32; mm; mm >>= 1) ss += __shfl_xor(ss, mm, 64);
      float rr = rsqrtf(ss * (1.f / 128.f) + 1e-6f);
      float y0 = x0 * rr * sk0, y1 = x1 * rr * sk1;
      float o0 = p4.x * y0 + p4.y * y1;
      float o1 = p4.z * y0 + p4.w * y1;
      *(unsigned*)(kb + dst) = (unsigned)f2bf(o0) | ((unsigned)f2bf(o1) << 16);
    }
  }

  {  // V -> LDS transposed
    const ushort_t* vsrc = qkv + (size_t)(bl0 + lane) * 9216 + 6144 + h * 128;
#pragma unroll
    for (int i = 0; i < 4; ++i) {
      int oct = w * 4 + i;
      ushort8 vv = *(const ushort8*)(vsrc + oct * 8);
#pragma unroll
      for (int j = 0; j < 8; ++j) {
        int d = oct * 8 + j;
        int ba = (d * 128 + lane * 2) ^ (j << 4);
        *(ushort_t*)((char*)Vt_lds + ba) = vv[j];
      }
    }
  }
  __syncthreads();

  {  // coalesced V^T rows to global [B,H,D,L]
    const int d = tid >> 1, half = tid & 1;
    ushort_t* orow = vtg + ((size_t)(b * 24 + h) * 128 + d) * 2048 + l0 + half * 32;
#pragma unroll
    for (int q = 0; q < 4; ++q) {
      int lb = d * 128 + half * 64 + q * 16;
      ushort8 vv = *(const ushort8*)((char*)Vt_lds + (lb ^ ((d & 7) << 4)));
      *(ushort8*)(orow + q * 8) = vv;
    }
  }
}

// ---------- 4) flash attention: swapped 32x32 structure ----------
__global__ __launch_bounds__(256, 2)
void attn_fwd(const ushort_t* __restrict__ qb, const ushort_t* __restrict__ kb,
              const ushort_t* __restrict__ vt, ushort_t* __restrict__ ob) {
  __shared__ ushort_t Ks[64 * 128];    // [key][d],  phys chunk = log ^ (key&15)
  __shared__ ushort_t Vts[128 * 64];   // [d][key],  phys chunk = log ^ (d&7)
  const int tid = threadIdx.x;
  const int w = tid >> 6, l = tid & 63;
  const int c = l & 31, hi = l >> 5;
  const int bh = blockIdx.y;
  const int q0 = blockIdx.x * 128 + w * 32;

  const ushort_t* qrow = qb + ((size_t)bh * 2048 + q0 + c) * 128;
  ushort8 qf[8];
#pragma unroll
  for (int s = 0; s < 8; ++s)
    qf[s] = *(const ushort8*)(qrow + s * 16 + hi * 8);

  f32x16 o[4];
#pragma unroll
  for (int dt = 0; dt < 4; ++dt) o[dt] = zero16();
  float m = -1e30f, lp = 0.f;   // m is wave-uniform; lp is row-c partial sum

  const ushort_t* kbase = kb + (size_t)bh * 2048 * 128;
  const ushort_t* vbase = vt + (size_t)bh * 128 * 2048;

  for (int kt = 0; kt < 2048; kt += 64) {
    __syncthreads();
#pragma unroll
    for (int i = 0; i < 4; ++i) {
      int u = w * 256 + i * 64 + l;
      int kr = u >> 4, kc = (u & 15) ^ (kr & 15);
      gload_lds16(kbase + (size_t)(kt + kr) * 128 + kc * 8,
                  Ks + (w * 256 + i * 64) * 8);
      int vr = u >> 3, vc = (u & 7) ^ (vr & 7);
      gload_lds16(vbase + (size_t)vr * 2048 + kt + vc * 8,
                  Vts + (w * 256 + i * 64) * 8);
    }
    __syncthreads();

    // S^T = K · Q^T : two 32-key tiles, 8 d-steps of k=16
    f32x16 s0 = zero16(), s1 = zero16();
#pragma unroll
    for (int ds = 0; ds < 8; ++ds) {
      int ch = (2 * ds + hi) ^ (c & 15);
      ushort8 k0 = *(const ushort8*)(Ks + c * 128 + ch * 8);
      ushort8 k1 = *(const ushort8*)(Ks + (32 + c) * 128 + ch * 8);
      s0 = mfma32(k0, qf[ds], s0);
      s1 = mfma32(k1, qf[ds], s1);
    }

    // online softmax (base-2), wave-uniform max, defer THR=8
    float p[32];
#pragma unroll
    for (int rr = 0; rr < 16; ++rr) { p[rr] = s0[rr]; p[16 + rr] = s1[rr]; }
    float pmax = p[0];
#pragma unroll
    for (int rr = 1; rr < 32; ++rr) pmax = fmaxf(pmax, p[rr]);
    if (!__all(pmax <= m + 8.f)) {
      float wm = pmax;
#pragma unroll
      for (int d = 1; d < 64; d <<= 1) wm = fmaxf(wm, __shfl_xor(wm, d, 64));
      float mn = fmaxf(m, wm);        // wave-uniform new max
      float fs = exp2f(m - mn);       // wave-uniform -> layout-independent
      m = mn;
      lp *= fs;
#pragma unroll
      for (int dt = 0; dt < 4; ++dt)
#pragma unroll
        for (int e = 0; e < 16; ++e) o[dt][e] *= fs;
    }
    float rs = 0.f;
#pragma unroll
    for (int rr = 0; rr < 32; ++rr) { p[rr] = exp2f(p[rr] - m); rs += p[rr]; }
    lp += rs;

    // P -> A-frag words: per 16-key step: 4 cvt_pk + 2 permlane32_swap
    uint32x4 pk[4];
#pragma unroll
    for (int ks = 0; ks < 4; ++ks) {
      unsigned a0 = cvtpk(p[ks * 8 + 0], p[ks * 8 + 1]);
      unsigned a1 = cvtpk(p[ks * 8 + 2], p[ks * 8 + 3]);
      unsigned a2 = cvtpk(p[ks * 8 + 4], p[ks * 8 + 5]);
      unsigned a3 = cvtpk(p[ks * 8 + 6], p[ks * 8 + 7]);
      swap32(a0, a2);
      swap32(a1, a3);
      pk[ks] = uint32x4{a0, a1, a2, a3};
    }

    // O += P · V : A = P-frag (regs), B = V-frag from V^T LDS
#pragma unroll
    for (int dt = 0; dt < 4; ++dt) {
#pragma unroll
      for (int ks = 0; ks < 4; ++ks) {
        int ch = (2 * ks + hi) ^ (c & 7);
        ushort8 vf = *(const ushort8*)(Vts + (32 * dt + c) * 64 + ch * 8);
        o[dt] = mfma32(__builtin_bit_cast(ushort8, pk[ks]), vf, o[dt]);
      }
    }
  }

  // epilogue: lr lives at lane q (row c); O rows are crow(r,hi) -> shfl
  float lr = lp + __shfl_xor(lp, 32, 64);
  float rl = 1.f / lr;
  const int b = bh / 24, h = bh % 24;
  ushort_t* obase = ob + ((size_t)b * 2048 + q0) * 3072 + h * 128 + c;
#pragma unroll
  for (int rr = 0; rr < 16; ++rr) {
    int q = (rr & 3) + 8 * (rr >> 2) + 4 * hi;
    float os = __shfl(rl, q, 64);   // denominator of row q
#pragma unroll
    for (int dt = 0; dt < 4; ++dt)
      obase[(size_t)q * 3072 + dt * 32] = f2bf(o[dt][rr] * os);
  }
}

// ---------- launch ----------
extern "C" void kernel_launch(void* const* d_in, const int* in_sizes, int n_in,
                              void* d_out, int out_size, void* d_ws, size_t ws_size,
                              hipStream_t stream) {
  const float* x    = (const float*)d_in[0];
  const float* pe   = (const float*)d_in[1];
  const float* qkvw = (const float*)d_in[2];
  const float* pw   = (const float*)d_in[3];
  const float* pb   = (const float*)d_in[4];
  const float* qsc  = (const float*)d_in[5];
  const float* ksc  = (const float*)d_in[6];
  float* out = (float*)d_out;

  char* p = (char*)d_ws;
  ushort_t* x_bf  = (ushort_t*)(p + 0);          // 25,165,824
  ushort_t* o_bf  = x_bf;                        // reuse: x dead after GEMM1
  ushort_t* qw_bf = (ushort_t*)(p + 25165824);   // 56,623,104
  ushort_t* pw_bf = (ushort_t*)(p + 81788928);   // 18,874,368
  ushort_t* qkv   = (ushort_t*)(p + 100663296);  // 75,497,472
  ushort_t* qh    = (ushort_t*)(p + 176160768);  // 25,165,824
  ushort_t* kh    = (ushort_t*)(p + 201326592);  // 25,165,824
  ushort_t* vtg   = (ushort_t*)(p + 226492416);  // 25,165,824 (V^T [B,H,D,L])

  cast_bf16<<<2048, 256, 0, stream>>>((const float4*)x,    (ushort4*)x_bf,  4096 * 3072 / 4);
  cast_bf16<<<2048, 256, 0, stream>>>((const float4*)qkvw, (ushort4*)qw_bf, 9216 * 3072 / 4);
  cast_bf16<<<2048, 256, 0, stream>>>((const float4*)pw,   (ushort4*)pw_bf, 3072 * 3072 / 4);

  gemm256<1, 0><<<dim3(36, 16), 512, 0, stream>>>(x_bf, qw_bf, nullptr, qkv, 4096, 9216, 3072);
  norm_rope<<<dim3(64, 24), 256, 0, stream>>>(qkv, pe, qsc, ksc, qh, kh, vtg);
  attn_fwd<<<dim3(16, 48), 256, 0, stream>>>(qh, kh, vtg, o_bf);
  gemm256<0, 1><<<dim3(12, 16), 512, 0, stream>>>(o_bf, pw_bf, pb, out, 4096, 3072, 3072);
}

// Round 6
// 522.006 us; speedup vs baseline: 1.7031x; 1.0774x over previous
//
#include <hip/hip_runtime.h>

typedef unsigned short ushort_t;
typedef unsigned short ushort8 __attribute__((ext_vector_type(8)));
typedef __bf16 bf16x8 __attribute__((ext_vector_type(8)));
typedef float f32x4 __attribute__((ext_vector_type(4)));
typedef float f32x16 __attribute__((ext_vector_type(16)));
typedef unsigned uint32x4 __attribute__((ext_vector_type(4)));

#define DEV __device__ __forceinline__

// ---------- helpers ----------
DEV ushort_t f2bf(float f) {
  unsigned u = __builtin_bit_cast(unsigned, f);
  u += 0x7FFFu + ((u >> 16) & 1u);   // RNE (no NaNs in this workload)
  return (ushort_t)(u >> 16);
}
DEV float bf2f(ushort_t u) {
  return __builtin_bit_cast(float, ((unsigned)u) << 16);
}
DEV void gload_lds16(const void* g, void* s) {
  __builtin_amdgcn_global_load_lds(
      (__attribute__((address_space(1))) void*)(size_t)g,
      (__attribute__((address_space(3))) void*)(size_t)s, 16, 0, 0);
}
DEV f32x4 mfma_bf16(ushort8 a, ushort8 b, f32x4 c) {
  return __builtin_amdgcn_mfma_f32_16x16x32_bf16(
      __builtin_bit_cast(bf16x8, a), __builtin_bit_cast(bf16x8, b), c, 0, 0, 0);
}
DEV f32x16 mfma32(ushort8 a, ushort8 b, f32x16 c) {
  return __builtin_amdgcn_mfma_f32_32x32x16_bf16(
      __builtin_bit_cast(bf16x8, a), __builtin_bit_cast(bf16x8, b), c, 0, 0, 0);
}
DEV f32x16 zero16() {
  f32x16 z;
#pragma unroll
  for (int i = 0; i < 16; ++i) z[i] = 0.f;
  return z;
}
DEV unsigned cvtpk(float lo, float hi2) {  // u32 = {bf16(hi2), bf16(lo)}
  unsigned r;
  asm("v_cvt_pk_bf16_f32 %0, %1, %2" : "=v"(r) : "v"(lo), "v"(hi2));
  return r;
}
// x'[l] = l<32 ? x[l] : y[l-32];  y'[l] = l<32 ? x[l+32] : y[l]
DEV void swap32(unsigned &x, unsigned &y) {
#if __has_builtin(__builtin_amdgcn_permlane32_swap)
  auto t = __builtin_amdgcn_permlane32_swap(x, y, false, false);
  x = (unsigned)t[0];
  y = (unsigned)t[1];
#else
  unsigned xs = (unsigned)__shfl_xor((int)x, 32, 64);
  unsigned ys = (unsigned)__shfl_xor((int)y, 32, 64);
  bool h = (threadIdx.x & 63) >= 32;
  unsigned nx = h ? ys : x;
  unsigned ny = h ? y : xs;
  x = nx; y = ny;
#endif
}
DEV void barx() {  // raw barrier, no vmcnt drain; compiler memory fence
  asm volatile("" ::: "memory");
  __builtin_amdgcn_s_barrier();
  asm volatile("" ::: "memory");
}
#define GATE_VM0 asm volatile("s_waitcnt vmcnt(0)" ::: "memory")
#define GATE_VM5 asm volatile("s_waitcnt vmcnt(5)" ::: "memory")
#define GATE_VM8 asm volatile("s_waitcnt vmcnt(8)" ::: "memory")

// ---------- 1) f32 -> bf16 cast ----------
__global__ void cast_bf16(const float4* __restrict__ in,
                          ushort4* __restrict__ out, int n4) {
  int stride = gridDim.x * blockDim.x;
  for (int i = blockIdx.x * blockDim.x + threadIdx.x; i < n4; i += stride) {
    float4 v = in[i];
    out[i] = make_ushort4(f2bf(v.x), f2bf(v.y), f2bf(v.z), f2bf(v.w));
  }
}

// ---------- 2) GEMM 256x192 8-phase (T1+T2+T3+T4+T5): C = A * Bw^T ----------
// BN=192 so grids are exact CU multiples: GEMM1 48x16=768 (3/CU), GEMM2
// 16x16=256 (1/CU) -> no dispatch-tail quantization (round-5: 75% util).
// 8 waves (2M x 4N), per-wave 128x48 out, BK=64, double-buffered LDS 112KiB.
// Staging per tile: A=4 instrs (A0..A3 by 64-row group), B=3. Order:
// first-5 = [A0,A2,B0,B1,B2] (needed ph1), last-2 = [A1,A3] (needed ph3).
// t+1 first-5 staged at t-1 ph4; t+1 last-2 at t ph1; single gate vmcnt(5)
// at t ph4 drains all of t+1, leaves t+2's first-5 in flight (never 0, T4).
template <int OUT_BF16, int ADD_BIAS>
__global__ __launch_bounds__(512, 2)
void gemmT(const ushort_t* __restrict__ A, const ushort_t* __restrict__ Bw,
           const float* __restrict__ bias, void* __restrict__ Cp,
           int M, int N, int K) {
  __shared__ ushort_t As[2][256 * 64];
  __shared__ ushort_t Bs[2][192 * 64];
  const int tid = threadIdx.x;
  const int w = tid >> 6, l = tid & 63;
  const int g = l >> 4, r = l & 15;
  const int wm = w >> 2, wn = w & 3;
  // XCD-chunked bijective swizzle (nwg % 8 == 0 for both grids)
  const int gx = gridDim.x;
  const int nwg = gx * gridDim.y;
  const int id = blockIdx.y * gx + blockIdx.x;
  const int swz = (id & 7) * (nwg >> 3) + (id >> 3);
  const int m0 = (swz / gx) * 256, n0 = (swz % gx) * 192;
  const int NT = K >> 6;

  // staging geometry: instr covers 64 rows; lane u -> row u>>3, chunk u&7;
  // source k-offset pre-swizzled: chunk ^ (row&7)  (both-sides, rule #21)
  int srow[4], soff[4];
#pragma unroll
  for (int i = 0; i < 4; ++i) {
    int u = i * 512 + tid;
    int row = u >> 3;
    srow[i] = row;
    soff[i] = ((u & 7) ^ (row & 7)) * 8;
  }

  auto stA = [&](int i, int t, int b) {
    gload_lds16(A + (size_t)(m0 + srow[i]) * K + t * 64 + soff[i],
                As[b] + (i * 512 + w * 64) * 8);
  };
  auto stB = [&](int i, int t, int b) {
    gload_lds16(Bw + (size_t)(n0 + srow[i]) * K + t * 64 + soff[i],
                Bs[b] + (i * 512 + w * 64) * 8);
  };
  auto rdA = [&](int b, int mi, int kk) -> ushort8 {
    int row = wm * 128 + mi * 16 + r;
    return *(const ushort8*)(As[b] + row * 64 + (((kk << 2) + g) ^ (r & 7)) * 8);
  };
  auto rdB = [&](int b, int ni, int kk) -> ushort8 {
    int col = wn * 48 + ni * 16 + r;
    return *(const ushort8*)(Bs[b] + col * 64 + (((kk << 2) + g) ^ (r & 7)) * 8);
  };

  f32x4 acc[8][3];
#pragma unroll
  for (int i = 0; i < 8; ++i)
#pragma unroll
    for (int j = 0; j < 3; ++j) acc[i][j] = f32x4{0.f, 0.f, 0.f, 0.f};

  ushort8 af[4][2], bf[3][2];

  // prologue: t0 all-7, t1 first-5; gate drains t0
  stA(0, 0, 0); stA(2, 0, 0);
  stB(0, 0, 0); stB(1, 0, 0); stB(2, 0, 0);
  stA(1, 0, 0); stA(3, 0, 0);
  {
    int t1 = (NT > 1) ? 1 : 0;
    stA(0, t1, 1); stA(2, t1, 1);
    stB(0, t1, 1); stB(1, t1, 1); stB(2, t1, 1);
  }
  GATE_VM5;
  barx();

  for (int t = 0; t < NT; ++t) {
    const int db = t & 1;
    const int ts1 = (t + 1 < NT) ? t + 1 : NT - 1;
    const int ts2 = (t + 2 < NT) ? t + 2 : NT - 1;

    // ---- ph1: rd A lo(8) + B lo(4); stage t+1 last-2 -> buf db^1
#pragma unroll
    for (int mi = 0; mi < 4; ++mi)
#pragma unroll
      for (int kk = 0; kk < 2; ++kk) af[mi][kk] = rdA(db, mi, kk);
#pragma unroll
    for (int ni = 0; ni < 2; ++ni)
#pragma unroll
      for (int kk = 0; kk < 2; ++kk) bf[ni][kk] = rdB(db, ni, kk);
    stA(1, ts1, db ^ 1); stA(3, ts1, db ^ 1);
    barx();
    __builtin_amdgcn_s_setprio(1);
#pragma unroll
    for (int mi = 0; mi < 4; ++mi)
#pragma unroll
      for (int ni = 0; ni < 2; ++ni)
#pragma unroll
        for (int kk = 0; kk < 2; ++kk)
          acc[mi][ni] = mfma_bf16(af[mi][kk], bf[ni][kk], acc[mi][ni]);
    __builtin_amdgcn_s_setprio(0);
    barx();

    // ---- ph2: rd B hi(2)
#pragma unroll
    for (int kk = 0; kk < 2; ++kk) bf[2][kk] = rdB(db, 2, kk);
    barx();
    __builtin_amdgcn_s_setprio(1);
#pragma unroll
    for (int mi = 0; mi < 4; ++mi)
#pragma unroll
      for (int kk = 0; kk < 2; ++kk)
        acc[mi][2] = mfma_bf16(af[mi][kk], bf[2][kk], acc[mi][2]);
    __builtin_amdgcn_s_setprio(0);
    barx();

    // ---- ph3: rd A hi(8)
#pragma unroll
    for (int mi = 0; mi < 4; ++mi)
#pragma unroll
      for (int kk = 0; kk < 2; ++kk) af[mi][kk] = rdA(db, mi + 4, kk);
    barx();
    __builtin_amdgcn_s_setprio(1);
#pragma unroll
    for (int mi = 0; mi < 4; ++mi)
#pragma unroll
      for (int ni = 0; ni < 2; ++ni)
#pragma unroll
        for (int kk = 0; kk < 2; ++kk)
          acc[mi + 4][ni] = mfma_bf16(af[mi][kk], bf[ni][kk], acc[mi + 4][ni]);
    __builtin_amdgcn_s_setprio(0);
    barx();

    // ---- ph4: stage t+2 first-5 -> buf db (t's reads done at ph3 end)
    stA(0, ts2, db); stA(2, ts2, db);
    stB(0, ts2, db); stB(1, ts2, db); stB(2, ts2, db);
    __builtin_amdgcn_s_setprio(1);
#pragma unroll
    for (int mi = 0; mi < 4; ++mi)
#pragma unroll
      for (int kk = 0; kk < 2; ++kk)
        acc[mi + 4][2] = mfma_bf16(af[mi][kk], bf[2][kk], acc[mi + 4][2]);
    __builtin_amdgcn_s_setprio(0);
    GATE_VM5;   // drains all 7 of t+1; leaves t+2's 5 in flight
    barx();
  }

  // epilogue: D row = 4g+j (M-dim), col = r (N-dim)
#pragma unroll
  for (int mi = 0; mi < 8; ++mi) {
#pragma unroll
    for (int ni = 0; ni < 3; ++ni) {
#pragma unroll
      for (int j = 0; j < 4; ++j) {
        int row = m0 + wm * 128 + mi * 16 + g * 4 + j;
        int col = n0 + wn * 48 + ni * 16 + r;
        float v = acc[mi][ni][j];
        if (ADD_BIAS) v += bias[col];
        if (OUT_BF16)
          ((ushort_t*)Cp)[(size_t)row * N + col] = f2bf(v);
        else
          ((float*)Cp)[(size_t)row * N + col] = v;
      }
    }
  }
}

// ---------- 3) RMSNorm + RoPE (Q,K row-major) + V transpose to [B,H,D,L] ----
__global__ __launch_bounds__(256)
void norm_rope(const ushort_t* __restrict__ qkv, const float* __restrict__ pe,
               const float* __restrict__ qs, const float* __restrict__ ksc,
               ushort_t* __restrict__ qb, ushort_t* __restrict__ kb,
               ushort_t* __restrict__ vtg) {
  __shared__ ushort_t Vt_lds[128 * 64];   // [d][token], XOR-swizzled
  const int tid = threadIdx.x;
  const int w = tid >> 6, lane = tid & 63;
  const int tb = blockIdx.x, h = blockIdx.y;
  const int bl0 = tb * 64;
  const int b = bl0 >> 11, l0 = bl0 & 2047;
  const int i2 = lane * 2;

  const float sq0 = qs[i2], sq1 = qs[i2 + 1];
  const float sk0 = ksc[i2], sk1 = ksc[i2 + 1];
  const float QSC = 0.12751744f;  // log2(e) / sqrt(128): softmax in base-2

  for (int t = 0; t < 16; ++t) {
    const int bl = bl0 + w * 16 + t;
    const float4 p4 = *(const float4*)(pe + (size_t)bl * 256 + lane * 4);
    const size_t src = (size_t)bl * 9216 + h * 128 + i2;
    const size_t dst = ((size_t)(b * 24 + h) * 2048 + (bl & 2047)) * 128 + i2;
    {  // Q
      unsigned u = *(const unsigned*)(qkv + src);
      float x0 = bf2f((ushort_t)(u & 0xFFFFu)), x1 = bf2f((ushort_t)(u >> 16));
      float ss = x0 * x0 + x1 * x1;
#pragma unroll
      for (int mm = 32; mm; mm >>= 1) ss += __shfl_xor(ss, mm, 64);
      float rr = rsqrtf(ss * (1.f / 128.f) + 1e-6f);
      float y0 = x0 * rr * sq0, y1 = x1 * rr * sq1;
      float o0 = (p4.x * y0 + p4.y * y1) * QSC;
      float o1 = (p4.z * y0 + p4.w * y1) * QSC;
      *(unsigned*)(qb + dst) = (unsigned)f2bf(o0) | ((unsigned)f2bf(o1) << 16);
    }
    {  // K
      unsigned u = *(const unsigned*)(qkv + src + 3072);
      float x0 = bf2f((ushort_t)(u & 0xFFFFu)), x1 = bf2f((ushort_t)(u >> 16));
      float ss = x0 * x0 + x1 * x1;
#pragma unroll
      for (int mm = 32; mm; mm >>= 1) ss += __shfl_xor(ss, mm, 64);
      float rr = rsqrtf(ss * (1.f / 128.f) + 1e-6f);
      float y0 = x0 * rr * sk0, y1 = x1 * rr * sk1;
      float o0 = p4.x * y0 + p4.y * y1;
      float o1 = p4.z * y0 + p4.w * y1;
      *(unsigned*)(kb + dst) = (unsigned)f2bf(o0) | ((unsigned)f2bf(o1) << 16);
    }
  }

  {  // V -> LDS transposed
    const ushort_t* vsrc = qkv + (size_t)(bl0 + lane) * 9216 + 6144 + h * 128;
#pragma unroll
    for (int i = 0; i < 4; ++i) {
      int oct = w * 4 + i;
      ushort8 vv = *(const ushort8*)(vsrc + oct * 8);
#pragma unroll
      for (int j = 0; j < 8; ++j) {
        int d = oct * 8 + j;
        int ba = (d * 128 + lane * 2) ^ (j << 4);
        *(ushort_t*)((char*)Vt_lds + ba) = vv[j];
      }
    }
  }
  __syncthreads();

  {  // coalesced V^T rows to global [B,H,D,L]
    const int d = tid >> 1, half = tid & 1;
    ushort_t* orow = vtg + ((size_t)(b * 24 + h) * 128 + d) * 2048 + l0 + half * 32;
#pragma unroll
    for (int q = 0; q < 4; ++q) {
      int lb = d * 128 + half * 64 + q * 16;
      ushort8 vv = *(const ushort8*)((char*)Vt_lds + (lb ^ ((d & 7) << 4)));
      *(ushort8*)(orow + q * 8) = vv;
    }
  }
}

// ---------- 4) flash attention: swapped 32x32, double-buffered K/V ----------
// Staging: stage t+1 -> buf db^1, gate vmcnt(8) (drains t's 8, leaves t+1's
// in flight across the whole compute -> HBM latency fully hidden), raw
// s_barrier (no vmcnt(0) drain). Trailing barrier guards next iter's WAR.
__global__ __launch_bounds__(256, 2)
void attn_fwd(const ushort_t* __restrict__ qb, const ushort_t* __restrict__ kb,
              const ushort_t* __restrict__ vt, ushort_t* __restrict__ ob) {
  __shared__ ushort_t Ks[2][64 * 128];    // [key][d], phys chunk = log ^ (key&15)
  __shared__ ushort_t Vts[2][128 * 64];   // [d][key], phys chunk = log ^ (d&7)
  const int tid = threadIdx.x;
  const int w = tid >> 6, l = tid & 63;
  const int c = l & 31, hi = l >> 5;
  // XCD-chunked swizzle (768 blocks, 16 q-tiles x 48 bh)
  const int id = blockIdx.y * 16 + blockIdx.x;
  const int swz = (id & 7) * 96 + (id >> 3);
  const int bh = swz >> 4;
  const int q0 = (swz & 15) * 128 + w * 32;

  const ushort_t* qrow = qb + ((size_t)bh * 2048 + q0 + c) * 128;
  ushort8 qf[8];
#pragma unroll
  for (int s = 0; s < 8; ++s)
    qf[s] = *(const ushort8*)(qrow + s * 16 + hi * 8);

  f32x16 o[4];
#pragma unroll
  for (int dt = 0; dt < 4; ++dt) o[dt] = zero16();
  float m = -1e30f, lp = 0.f;   // m wave-uniform; lp row-c partial sum

  const ushort_t* kbase = kb + (size_t)bh * 2048 * 128;
  const ushort_t* vbase = vt + (size_t)bh * 128 * 2048;

  auto stage = [&](int t, int b) {
#pragma unroll
    for (int i = 0; i < 4; ++i) {
      int u = w * 256 + i * 64 + l;
      int kr = u >> 4, kc = (u & 15) ^ (kr & 15);
      gload_lds16(kbase + (size_t)(t * 64 + kr) * 128 + kc * 8,
                  Ks[b] + (w * 256 + i * 64) * 8);
      int vr = u >> 3, vc = (u & 7) ^ (vr & 7);
      gload_lds16(vbase + (size_t)vr * 2048 + t * 64 + vc * 8,
                  Vts[b] + (w * 256 + i * 64) * 8);
    }
  };

  stage(0, 0);   // prologue

  for (int t = 0; t < 32; ++t) {
    const int db = t & 1;
    if (t < 31) {
      stage(t + 1, db ^ 1);
      GATE_VM8;          // drains tile t's 8; t+1's stay in flight
    } else {
      GATE_VM0;
    }
    barx();

    // S^T = K . Q^T : two 32-key tiles, 8 d-steps of k=16
    f32x16 s0 = zero16(), s1 = zero16();
    __builtin_amdgcn_s_setprio(1);
#pragma unroll
    for (int ds = 0; ds < 8; ++ds) {
      int ch = (2 * ds + hi) ^ (c & 15);
      ushort8 k0 = *(const ushort8*)(Ks[db] + c * 128 + ch * 8);
      ushort8 k1 = *(const ushort8*)(Ks[db] + (32 + c) * 128 + ch * 8);
      s0 = mfma32(k0, qf[ds], s0);
      s1 = mfma32(k1, qf[ds], s1);
    }
    __builtin_amdgcn_s_setprio(0);

    // online softmax (base-2), wave-uniform max, defer THR=8
    float p[32];
#pragma unroll
    for (int rr = 0; rr < 16; ++rr) { p[rr] = s0[rr]; p[16 + rr] = s1[rr]; }
    float pmax = p[0];
#pragma unroll
    for (int rr = 1; rr < 32; ++rr) pmax = fmaxf(pmax, p[rr]);
    if (!__all(pmax <= m + 8.f)) {
      float wm = pmax;
#pragma unroll
      for (int d = 1; d < 64; d <<= 1) wm = fmaxf(wm, __shfl_xor(wm, d, 64));
      float mn = fmaxf(m, wm);        // wave-uniform new max
      float fs = exp2f(m - mn);       // layout-independent rescale
      m = mn;
      lp *= fs;
#pragma unroll
      for (int dt = 0; dt < 4; ++dt)
#pragma unroll
        for (int e = 0; e < 16; ++e) o[dt][e] *= fs;
    }
    float rs = 0.f;
#pragma unroll
    for (int rr = 0; rr < 32; ++rr) { p[rr] = exp2f(p[rr] - m); rs += p[rr]; }
    lp += rs;

    // P -> A-frag words: 4 cvt_pk + 2 permlane32_swap per 16-key step (T12)
    uint32x4 pk[4];
#pragma unroll
    for (int ks = 0; ks < 4; ++ks) {
      unsigned a0 = cvtpk(p[ks * 8 + 0], p[ks * 8 + 1]);
      unsigned a1 = cvtpk(p[ks * 8 + 2], p[ks * 8 + 3]);
      unsigned a2 = cvtpk(p[ks * 8 + 4], p[ks * 8 + 5]);
      unsigned a3 = cvtpk(p[ks * 8 + 6], p[ks * 8 + 7]);
      swap32(a0, a2);
      swap32(a1, a3);
      pk[ks] = uint32x4{a0, a1, a2, a3};
    }

    // O += P . V
    __builtin_amdgcn_s_setprio(1);
#pragma unroll
    for (int dt = 0; dt < 4; ++dt) {
#pragma unroll
      for (int ks = 0; ks < 4; ++ks) {
        int ch = (2 * ks + hi) ^ (c & 7);
        ushort8 vf = *(const ushort8*)(Vts[db] + (32 * dt + c) * 64 + ch * 8);
        o[dt] = mfma32(__builtin_bit_cast(ushort8, pk[ks]), vf, o[dt]);
      }
    }
    __builtin_amdgcn_s_setprio(0);
    barx();   // WAR guard: next iter stages into buf db
  }

  // epilogue: lr lives at lane q (row c); O rows are crow(r,hi) -> shfl
  float lr = lp + __shfl_xor(lp, 32, 64);
  float rl = 1.f / lr;
  const int b = bh / 24, h = bh % 24;
  ushort_t* obase = ob + ((size_t)b * 2048 + q0) * 3072 + h * 128 + c;
#pragma unroll
  for (int rr = 0; rr < 16; ++rr) {
    int q = (rr & 3) + 8 * (rr >> 2) + 4 * hi;
    float os = __shfl(rl, q, 64);   // denominator of row q
#pragma unroll
    for (int dt = 0; dt < 4; ++dt)
      obase[(size_t)q * 3072 + dt * 32] = f2bf(o[dt][rr] * os);
  }
}

// ---------- launch ----------
extern "C" void kernel_launch(void* const* d_in, const int* in_sizes, int n_in,
                              void* d_out, int out_size, void* d_ws, size_t ws_size,
                              hipStream_t stream) {
  const float* x    = (const float*)d_in[0];
  const float* pe   = (const float*)d_in[1];
  const float* qkvw = (const float*)d_in[2];
  const float* pw   = (const float*)d_in[3];
  const float* pb   = (const float*)d_in[4];
  const float* qsc  = (const float*)d_in[5];
  const float* ksc  = (const float*)d_in[6];
  float* out = (float*)d_out;

  char* p = (char*)d_ws;
  ushort_t* x_bf  = (ushort_t*)(p + 0);          // 25,165,824
  ushort_t* o_bf  = x_bf;                        // reuse: x dead after GEMM1
  ushort_t* qw_bf = (ushort_t*)(p + 25165824);   // 56,623,104
  ushort_t* pw_bf = (ushort_t*)(p + 81788928);   // 18,874,368
  ushort_t* qkv   = (ushort_t*)(p + 100663296);  // 75,497,472
  ushort_t* qh    = (ushort_t*)(p + 176160768);  // 25,165,824
  ushort_t* kh    = (ushort_t*)(p + 201326592);  // 25,165,824
  ushort_t* vtg   = (ushort_t*)(p + 226492416);  // 25,165,824 (V^T [B,H,D,L])

  cast_bf16<<<2048, 256, 0, stream>>>((const float4*)x,    (ushort4*)x_bf,  4096 * 3072 / 4);
  cast_bf16<<<2048, 256, 0, stream>>>((const float4*)qkvw, (ushort4*)qw_bf, 9216 * 3072 / 4);
  cast_bf16<<<2048, 256, 0, stream>>>((const float4*)pw,   (ushort4*)pw_bf, 3072 * 3072 / 4);

  gemmT<1, 0><<<dim3(48, 16), 512, 0, stream>>>(x_bf, qw_bf, nullptr, qkv, 4096, 9216, 3072);
  norm_rope<<<dim3(64, 24), 256, 0, stream>>>(qkv, pe, qsc, ksc, qh, kh, vtg);
  attn_fwd<<<dim3(16, 48), 256, 0, stream>>>(qh, kh, vtg, o_bf);
  gemmT<0, 1><<<dim3(16, 16), 512, 0, stream>>>(o_bf, pw_bf, pb, out, 4096, 3072, 3072);
}